// Round 1
// baseline (282.140 us; speedup 1.0000x reference)
//
#include <hip/hip_runtime.h>

// ---------------------------------------------------------------------------
// LongTermMemoryModule, round 9. FP32 in/out. Changes vs r8:
//  - attn_partial keeps P entirely in registers: the PV key axis is a
//    summation index, so V^T is stored with a per-32-block key permutation
//    (applied free in proj_fused's copy-out) that makes the QK C-layout
//    (keys qd*4+r per lane) directly usable as the PV A-fragment
//    (keys qd*8+j) for full-rate 16x16x32 MFMA. This deletes the Plds
//    double buffer (36 KB), all 16 DS ops/iter, and both lgkmcnt(0)
//    scheduling fences -- the round-8 latency serializer.
//  - wave decomposition re-split: each wave owns 32 s-rows x 1024 keys
//    (was 64 x 512): same MFMA/exp count, oacc+bQ register pressure halved.
// Shapes: B=32 S=64 D=512 M=8192 H=8 hd=64.
// ---------------------------------------------------------------------------

#define Dm  512
#define Mb  8192
#define BSr 2048

// 0.125 (1/sqrt(hd)) * log2(e): exp2 after pre-scaled QK == softmax exp
#define QSCALE 0.18033688011112042f

typedef float f32x4 __attribute__((ext_vector_type(4)));
typedef short bf16x4 __attribute__((ext_vector_type(4)));
typedef short bf16x8 __attribute__((ext_vector_type(8)));
typedef unsigned short u16x4 __attribute__((ext_vector_type(4)));
typedef unsigned short u16x8 __attribute__((ext_vector_type(8)));
typedef unsigned u32x4 __attribute__((ext_vector_type(4)));

#define MFMA(a, b, c) __builtin_amdgcn_mfma_f32_16x16x32_bf16((a), (b), (c), 0, 0, 0)

#if __has_builtin(__builtin_amdgcn_exp2f)
#define EXP2F(x) __builtin_amdgcn_exp2f(x)
#else
#define EXP2F(x) __expf((x)*0.6931471805599453f)
#endif

__device__ __forceinline__ unsigned short f32_bf16(float f) {
  unsigned u = __builtin_bit_cast(unsigned, f);
  u += 0x7FFFu + ((u >> 16) & 1u);   // RNE
  return (unsigned short)(u >> 16);
}
__device__ __forceinline__ float bf16_f32(unsigned short h) {
  unsigned u = ((unsigned)h) << 16;
  return __builtin_bit_cast(float, u);
}
__device__ __forceinline__ unsigned pack_bf16_trunc(float a, float b) {
  // low half <- bf16(a), high half <- bf16(b); truncation rounding
  return (__builtin_bit_cast(unsigned, a) >> 16) |
         (__builtin_bit_cast(unsigned, b) & 0xFFFF0000u);
}

// ---------------------------------------------------------------------------
// Merged fp32 -> bf16 canonicalization of all 6 tensors (4 elems/thread).
// ---------------------------------------------------------------------------
__global__ __launch_bounds__(256) void convert_all(
    const float* __restrict__ q, const float* __restrict__ bank,
    const float* __restrict__ Win, const float* __restrict__ bin,
    const float* __restrict__ Wout, const float* __restrict__ bout,
    unsigned short* __restrict__ q_c, unsigned short* __restrict__ bank_c,
    unsigned short* __restrict__ Win_c, unsigned short* __restrict__ bin_c,
    unsigned short* __restrict__ Wout_c, unsigned short* __restrict__ bout_c) {
  const int e = (blockIdx.x * 256 + threadIdx.x) * 4;
  const float* src; unsigned short* dst; int off;
  if (e < 1048576)      { src = q;    dst = q_c;    off = e; }
  else if (e < 5242880) { src = bank; dst = bank_c; off = e - 1048576; }
  else if (e < 6029312) { src = Win;  dst = Win_c;  off = e - 5242880; }
  else if (e < 6030848) { src = bin;  dst = bin_c;  off = e - 6029312; }
  else if (e < 6292992) { src = Wout; dst = Wout_c; off = e - 6030848; }
  else                  { src = bout; dst = bout_c; off = e - 6292992; }
  f32x4 v = *(const f32x4*)(src + off);
  u16x4 o;
#pragma unroll
  for (int j = 0; j < 4; ++j) o[j] = f32_bf16(v[j]);
  *(u16x4*)(dst + off) = o;
}

// ---------------------------------------------------------------------------
// Fused projections. Blocks [0,128): Q projection (q_s[bh][s][d], pre-scaled
// by QSCALE). Blocks [128,640): K+V projection (k_s[h][m][d], vT_s[h*64+d][m],
// LDS-staged coalesced stores). vT_s columns are key-permuted inside each
// 32-block: col x holds V[key = (x>>5)*32 + ((x&7)>>2)*16 + ((x>>3)&3)*4
// + (x&3)] so attn's PV B-frag (bf16x8 at qd*8) matches the QK C-layout.
// ---------------------------------------------------------------------------
__global__ __launch_bounds__(256) void proj_fused(
    const unsigned short* __restrict__ q_c,
    const unsigned short* __restrict__ bank_c,
    const unsigned short* __restrict__ Win_c,
    const unsigned short* __restrict__ bin_c,
    unsigned short* __restrict__ q_s,
    unsigned short* __restrict__ k_s,
    unsigned short* __restrict__ vT_s) {
  __shared__ __align__(16) unsigned short Kst[128 * 72];
  __shared__ __align__(16) unsigned short Vst[64 * 136];
  const int lane = threadIdx.x & 63;
  const int wv   = threadIdx.x >> 6;
  const int l15  = lane & 15;
  const int qd   = lane >> 4;
  const f32x4 z4 = {0.f, 0.f, 0.f, 0.f};

  if (blockIdx.x < 128) {
    // ---------------- Q projection ----------------
    const int mbase = (blockIdx.x >> 3) * 128 + wv * 32;
    const int nbase = (blockIdx.x & 7) * 64;
    f32x4 acc[2][4];
#pragma unroll
    for (int ti = 0; ti < 2; ++ti)
#pragma unroll
      for (int j = 0; j < 4; ++j) acc[ti][j] = z4;

    const unsigned short* a0p = q_c + (mbase + l15) * Dm + qd * 8;
    const unsigned short* a1p = a0p + 16 * Dm;
    const unsigned short* wp  = Win_c + (nbase + l15) * Dm + qd * 8;

#pragma unroll 4
    for (int k0 = 0; k0 < Dm; k0 += 32) {
      bf16x8 a0 = *(const bf16x8*)(a0p + k0);
      bf16x8 a1 = *(const bf16x8*)(a1p + k0);
#pragma unroll
      for (int j = 0; j < 4; ++j) {
        bf16x8 b = *(const bf16x8*)(wp + j * 16 * Dm + k0);
        acc[0][j] = MFMA(a0, b, acc[0][j]);
        acc[1][j] = MFMA(a1, b, acc[1][j]);
      }
    }
#pragma unroll
    for (int ti = 0; ti < 2; ++ti) {
#pragma unroll
      for (int j = 0; j < 4; ++j) {
        const int n = nbase + j * 16 + l15;
        const float bf = bf16_f32(bin_c[n]);
#pragma unroll
        for (int r = 0; r < 4; ++r) {
          const int m = mbase + ti * 16 + qd * 4 + r;
          const unsigned idx = ((unsigned)(m >> 6) * 8u + (unsigned)(n >> 6)) * 4096u +
                               (unsigned)(m & 63) * 64u + (unsigned)(n & 63);
          q_s[idx] = f32_bf16((acc[ti][j][r] + bf) * QSCALE);
        }
      }
    }
    return;
  }

  // ---------------- K+V projection ----------------
  const int idx  = blockIdx.x - 128;
  const int h     = idx >> 6;
  const int mbase = (idx & 63) * 128;

  f32x4 kacc[2][4], vacc[2][4];
#pragma unroll
  for (int ti = 0; ti < 2; ++ti)
#pragma unroll
    for (int j = 0; j < 4; ++j) { kacc[ti][j] = z4; vacc[ti][j] = z4; }

  const unsigned short* a0p = bank_c + (mbase + wv * 32 + l15) * Dm + qd * 8;
  const unsigned short* a1p = a0p + 16 * Dm;
  const unsigned short* wkp = Win_c + (Dm + h * 64 + l15) * Dm + qd * 8;
  const unsigned short* wvp = Win_c + (2 * Dm + h * 64 + l15) * Dm + qd * 8;

#pragma unroll 2
  for (int k0 = 0; k0 < Dm; k0 += 32) {
    bf16x8 a0 = *(const bf16x8*)(a0p + k0);
    bf16x8 a1 = *(const bf16x8*)(a1p + k0);
#pragma unroll
    for (int j = 0; j < 4; ++j) {
      bf16x8 wk  = *(const bf16x8*)(wkp + j * 16 * Dm + k0);
      bf16x8 wvv = *(const bf16x8*)(wvp + j * 16 * Dm + k0);
      kacc[0][j] = MFMA(a0, wk, kacc[0][j]);
      kacc[1][j] = MFMA(a1, wk, kacc[1][j]);
      vacc[0][j] = MFMA(a0, wvv, vacc[0][j]);
      vacc[1][j] = MFMA(a1, wvv, vacc[1][j]);
    }
  }

#pragma unroll
  for (int ti = 0; ti < 2; ++ti) {
#pragma unroll
    for (int j = 0; j < 4; ++j) {
      const int d = j * 16 + l15;
      const float bk = bf16_f32(bin_c[Dm + h * 64 + d]);
      const float bv = bf16_f32(bin_c[2 * Dm + h * 64 + d]);
#pragma unroll
      for (int r = 0; r < 4; ++r) {
        const int m = wv * 32 + ti * 16 + qd * 4 + r;
        Kst[m * 72 + d]  = f32_bf16(kacc[ti][j][r] + bk);
        Vst[d * 136 + m] = f32_bf16(vacc[ti][j][r] + bv);
      }
    }
  }
  __syncthreads();

#pragma unroll
  for (int p = 0; p < 4; ++p) {
    const int m = p * 32 + (threadIdx.x >> 3);
    const int d = (threadIdx.x & 7) * 8;
    *(u16x8*)(k_s + h * (Mb * 64) + (mbase + m) * 64 + d) =
        *(const u16x8*)(Kst + m * 72 + d);
  }
  // V copy-out applies the key permutation: dest cols x=m16*8..+7 pull
  // sources {base+q4..+3, base+16+q4..+3}. Two b64 LDS reads, 2-way banked.
#pragma unroll
  for (int p = 0; p < 4; ++p) {
    const int d    = p * 16 + (threadIdx.x >> 4);
    const int m16  = threadIdx.x & 15;
    const int base = (m16 >> 2) * 32;
    const int q4   = (m16 & 3) * 4;
    u16x4 lo = *(const u16x4*)(Vst + d * 136 + base + q4);
    u16x4 hi = *(const u16x4*)(Vst + d * 136 + base + 16 + q4);
    u16x8 o  = __builtin_shufflevector(lo, hi, 0, 1, 2, 3, 4, 5, 6, 7);
    *(u16x8*)(vT_s + (h * 64 + d) * Mb + mbase + m16 * 8) = o;
  }
}

// ---------------------------------------------------------------------------
// Attention partial, S^T formulation, register-resident P.
// Block = (bh, part). Wave wv owns s-rows (wv>>1)*32..+31 and keys
// part*2048 + (wv&1)*1024 .. +1023, walked in 16 strips of 64 keys.
// Per strip: QK (8 K loads, 16 MFMA) -> exp2+pack (32 exp, 16 pack)
// -> PV (8 V loads, 16 MFMA). No LDS, no barriers in the loop: the packed
// exp values ARE the PV A-fragment because vT_s is key-permuted.
// ---------------------------------------------------------------------------
__global__ __launch_bounds__(256) void attn_partial(
    const unsigned short* __restrict__ q_s,   // [bh][s][d], pre-scaled
    const unsigned short* __restrict__ k_s,   // [h][m][d]
    const unsigned short* __restrict__ vT_s,  // [h][d][m], keyperm'd per 32
    unsigned short* __restrict__ O_part,      // [bh][part][s][d] bf16
    float* __restrict__ l_part) {             // [bh][part][s]
  __shared__ __align__(16) float red[2048];   // 8 KB: pairwise O reduce
  __shared__ float lred[4][32];

  const int lane = threadIdx.x & 63;
  const int wv   = threadIdx.x >> 6;
  const int l15  = lane & 15;
  const int qd   = lane >> 4;
  const int bh   = blockIdx.x >> 2;
  const int part = blockIdx.x & 3;
  const int h    = bh & 7;

  const unsigned short* qp = q_s + bh * 4096;
  const unsigned short* kp = k_s + h * (Mb * 64);
  const unsigned short* vp = vT_s + h * (Mb * 64);

  // Q as B-operand: B[k=d][n=s], n = l15 -> rows sbase + sj*16 + l15
  const int sbase = (wv >> 1) * 32;
  bf16x8 bQ[2][2];
#pragma unroll
  for (int sj = 0; sj < 2; ++sj)
#pragma unroll
    for (int ks = 0; ks < 2; ++ks)
      bQ[sj][ks] = *(const bf16x8*)(qp + (sbase + sj * 16 + l15) * 64 + ks * 32 + qd * 8);

  const f32x4 z4 = {0.f, 0.f, 0.f, 0.f};
  f32x4 oacc[2][4];
  float lsum[2] = {0.f, 0.f};
#pragma unroll
  for (int sj = 0; sj < 2; ++sj)
#pragma unroll
    for (int dt = 0; dt < 4; ++dt) oacc[sj][dt] = z4;

  const int mwv = part * 2048 + (wv & 1) * 1024;

#pragma unroll 2
  for (int it = 0; it < 16; ++it) {
    const int m0 = mwv + it * 64;

    // ---- QK: S^T = K·Q^T. C layout: col=l15=s, row=qd*4+r=key ----
    f32x4 sfr[4][2];
#pragma unroll
    for (int kt = 0; kt < 4; ++kt)
#pragma unroll
      for (int sj = 0; sj < 2; ++sj) sfr[kt][sj] = z4;
#pragma unroll
    for (int kt = 0; kt < 4; ++kt) {
#pragma unroll
      for (int ks = 0; ks < 2; ++ks) {
        bf16x8 aK = *(const bf16x8*)(kp + (m0 + kt * 16 + l15) * 64 + ks * 32 + qd * 8);
#pragma unroll
        for (int sj = 0; sj < 2; ++sj) sfr[kt][sj] = MFMA(aK, bQ[sj][ks], sfr[kt][sj]);
      }
    }

    // ---- exp2 + pack: lane's 8 values per (sj, 32-key chunk) are exactly
    //      the PV A-fragment under the key permutation ----
    bf16x8 aP[2][2];
#pragma unroll
    for (int sj = 0; sj < 2; ++sj) {
#pragma unroll
      for (int c = 0; c < 2; ++c) {
        const f32x4 lo = sfr[c * 2][sj];
        const f32x4 hi = sfr[c * 2 + 1][sj];
        float e0 = EXP2F(lo[0]), e1 = EXP2F(lo[1]);
        float e2 = EXP2F(lo[2]), e3 = EXP2F(lo[3]);
        float e4 = EXP2F(hi[0]), e5 = EXP2F(hi[1]);
        float e6 = EXP2F(hi[2]), e7 = EXP2F(hi[3]);
        lsum[sj] += ((e0 + e1) + (e2 + e3)) + ((e4 + e5) + (e6 + e7));
        u32x4 pk;
        pk[0] = pack_bf16_trunc(e0, e1);
        pk[1] = pack_bf16_trunc(e2, e3);
        pk[2] = pack_bf16_trunc(e4, e5);
        pk[3] = pack_bf16_trunc(e6, e7);
        aP[sj][c] = __builtin_bit_cast(bf16x8, pk);
      }
    }

    // ---- PV: O += P·Vperm ----
#pragma unroll
    for (int c = 0; c < 2; ++c) {
#pragma unroll
      for (int dt = 0; dt < 4; ++dt) {
        bf16x8 bV = *(const bf16x8*)(vp + (dt * 16 + l15) * Mb + m0 + c * 32 + qd * 8);
#pragma unroll
        for (int sj = 0; sj < 2; ++sj) oacc[sj][dt] = MFMA(aP[sj][c], bV, oacc[sj][dt]);
      }
    }
  }

  // --- l: lane holds partial for s = sbase + sj*16 + l15; reduce quads ---
#pragma unroll
  for (int sj = 0; sj < 2; ++sj) {
    float v = lsum[sj];
    v += __shfl_xor(v, 16);
    v += __shfl_xor(v, 32);
    if (qd == 0) lred[wv][sj * 16 + l15] = v;
  }
  __syncthreads();
  if (threadIdx.x < 64) {
    const int hi = threadIdx.x >> 5;
    const int lo = threadIdx.x & 31;
    l_part[(bh * 4 + part) * 64 + threadIdx.x] =
        lred[hi * 2][lo] + lred[hi * 2 + 1][lo];
  }

  // --- O: pairwise wave reduce per s-tile ti (waves ti>>1*2, +1 own it) ---
  unsigned short* Ob = O_part + (bh * 4 + part) * 4096;
  for (int ti = 0; ti < 4; ++ti) {
    __syncthreads();
    if ((wv >> 1) == (ti >> 1)) {
      const int tl = ti & 1;
#pragma unroll
      for (int dt = 0; dt < 4; ++dt)
#pragma unroll
        for (int r = 0; r < 4; ++r)
          red[(wv & 1) * 1024 + dt * 256 + r * 64 + lane] = oacc[tl][dt][r];
    }
    __syncthreads();
#pragma unroll
    for (int j = 0; j < 4; ++j) {
      const int idx = j * 256 + threadIdx.x;
      const float s = red[idx] + red[1024 + idx];
      const int ln = idx & 63;
      const int r  = (idx >> 6) & 3;
      const int dt = idx >> 8;
      const int srow = ti * 16 + (ln >> 4) * 4 + r;
      const int dcol = dt * 16 + (ln & 15);
      Ob[srow * 64 + dcol] = f32_bf16(s);
    }
  }
}

// ---------------------------------------------------------------------------
// Fused: blocks [0,1024) combine attention partials -> a_stage bf16;
// blocks [1024,5120) write new_bank fp32 (overwrites the K/V scratch).
// Both depend only on attn_partial; disjoint memory.
// ---------------------------------------------------------------------------
__global__ __launch_bounds__(256) void combine_bank(
    const unsigned short* __restrict__ O_part, const float* __restrict__ l_part,
    unsigned short* __restrict__ a_stage,
    const float* __restrict__ memory, const float* __restrict__ bank,
    const int* __restrict__ ptrp, float* __restrict__ out_bank) {
  if (blockIdx.x < 1024) {
    const int e  = (blockIdx.x * 256 + threadIdx.x) * 4;  // < 1048576
    const int bh = e >> 12;
    const int rem = e & 4095;
    const int s  = rem >> 6;
    const int d  = rem & 63;
    float acc[4] = {0.f, 0.f, 0.f, 0.f};
    float l = 0.f;
#pragma unroll
    for (int p = 0; p < 4; ++p) {
      u16x4 v = *(const u16x4*)(O_part + (bh * 4 + p) * 4096 + rem);
#pragma unroll
      for (int j = 0; j < 4; ++j) acc[j] += bf16_f32(v[j]);
      l += l_part[(bh * 4 + p) * 64 + s];
    }
    const int b = bh >> 3, h = bh & 7;
    u16x4 o;
#pragma unroll
    for (int j = 0; j < 4; ++j) o[j] = f32_bf16(acc[j] / l);
    *(u16x4*)(a_stage + (b * 64 + s) * 512 + h * 64 + d) = o;
  } else {
    const int t  = (blockIdx.x - 1024) * 256 + threadIdx.x;  // < 1,048,576
    const int r  = t >> 7;
    const int c4 = (t & 127) * 4;
    const int ptr = ptrp[0];
    const unsigned off = (unsigned)(r - ptr + Mb) & (Mb - 1);
    const float* src = (off < (unsigned)BSr) ? memory + off * Dm + c4
                                             : bank + r * Dm + c4;
    *(f32x4*)(out_bank + r * Dm + c4) = *(const f32x4*)src;
  }
}

// ---------------------------------------------------------------------------
// retrieved[m,n] = a_stage[m,:] @ Wout[n,:] + bout[n]  -> fp32 d_out.
// ---------------------------------------------------------------------------
__global__ __launch_bounds__(256) void out_proj(
    const unsigned short* __restrict__ A,
    const unsigned short* __restrict__ W,
    const unsigned short* __restrict__ bias,
    float* __restrict__ out) {
  const int lane = threadIdx.x & 63;
  const int wv   = threadIdx.x >> 6;
  const int l15  = lane & 15;
  const int qd   = lane >> 4;
  const int mbase = blockIdx.y * 128 + wv * 32;
  const int nbase = blockIdx.x * 64;

  const f32x4 z4 = {0.f, 0.f, 0.f, 0.f};
  f32x4 acc[2][4];
#pragma unroll
  for (int ti = 0; ti < 2; ++ti)
#pragma unroll
    for (int j = 0; j < 4; ++j) acc[ti][j] = z4;

  const unsigned short* a0p = A + (mbase + l15) * Dm + qd * 8;
  const unsigned short* a1p = a0p + 16 * Dm;
  const unsigned short* wp  = W + (nbase + l15) * Dm + qd * 8;

#pragma unroll 4
  for (int k0 = 0; k0 < Dm; k0 += 32) {
    bf16x8 a0 = *(const bf16x8*)(a0p + k0);
    bf16x8 a1 = *(const bf16x8*)(a1p + k0);
#pragma unroll
    for (int j = 0; j < 4; ++j) {
      bf16x8 bfr = *(const bf16x8*)(wp + j * 16 * Dm + k0);
      acc[0][j] = MFMA(a0, bfr, acc[0][j]);
      acc[1][j] = MFMA(a1, bfr, acc[1][j]);
    }
  }

#pragma unroll
  for (int ti = 0; ti < 2; ++ti) {
#pragma unroll
    for (int j = 0; j < 4; ++j) {
      const int n = nbase + j * 16 + l15;
      const float bf = bf16_f32(bias[n]);
#pragma unroll
      for (int r = 0; r < 4; ++r) {
        const int m = mbase + ti * 16 + qd * 4 + r;
        out[m * Dm + n] = acc[ti][j][r] + bf;
      }
    }
  }
}

// ---------------------------------------------------------------------------
extern "C" void kernel_launch(void* const* d_in, const int* in_sizes, int n_in,
                              void* d_out, int out_size, void* d_ws, size_t ws_size,
                              hipStream_t stream) {
  const float* query = (const float*)d_in[0];
  const float* memry = (const float*)d_in[1];
  const float* bank  = (const float*)d_in[2];
  const float* Win   = (const float*)d_in[3];
  const float* bin   = (const float*)d_in[4];
  const float* Wout  = (const float*)d_in[5];
  const float* bout  = (const float*)d_in[6];
  const int*   ptrp  = (const int*)d_in[7];
  float* outf = (float*)d_out;

  // ws layout (14.3 MB; 15.8 MB proven). Lifetime-disjoint aliases:
  // a_stage reuses q_c; O_part reuses bank_c.
  char* ws = (char*)d_ws;
  unsigned short* q_c     = (unsigned short*)(ws);                 //  0 ..  2 MB
  unsigned short* a_stage = (unsigned short*)(ws);                 //  (alias)
  unsigned short* bank_c  = (unsigned short*)(ws + (2u << 20));    //  2 .. 10 MB
  unsigned short* O_part  = (unsigned short*)(ws + (2u << 20));    //  (alias)
  unsigned short* Win_c   = (unsigned short*)(ws + (10u << 20));   // 10 .. 11.5 MB
  unsigned short* Wout_c  = (unsigned short*)(ws + 12058624u);     // 11.5 .. 12 MB
  unsigned short* q_s     = (unsigned short*)(ws + (12u << 20));   // 12 .. 14 MB
  float*          l_part  = (float*)(ws + (14u << 20));            // 14 .. 14.25 MB
  unsigned short* bin_c   = (unsigned short*)(ws + 14942208u);
  unsigned short* bout_c  = (unsigned short*)(ws + 14945280u);

  // K/V scratch in d_out's bank region; combine_bank rewrites it afterwards.
  unsigned short* kv = (unsigned short*)(outf + 1048576);
  unsigned short* k_s  = kv;             // 8 MB: [h][m][d]
  unsigned short* vT_s = kv + 4194304;   // 8 MB: [h][d][m] (keyperm'd)

  convert_all<<<6146, 256, 0, stream>>>(query, bank, Win, bin, Wout, bout,
                                        q_c, bank_c, Win_c, bin_c, Wout_c, bout_c);

  proj_fused<<<640, 256, 0, stream>>>(q_c, bank_c, Win_c, bin_c, q_s, k_s, vT_s);

  attn_partial<<<1024, 256, 0, stream>>>(q_s, k_s, vT_s, O_part, l_part);

  combine_bank<<<5120, 256, 0, stream>>>(O_part, l_part, a_stage,
                                         memry, bank, ptrp, outf + 1048576);

  out_proj<<<dim3(8, 16), 256, 0, stream>>>(a_stage, Wout_c, bout_c, outf);
}

// Round 2
// 237.796 us; speedup vs baseline: 1.1865x; 1.1865x over previous
//
#include <hip/hip_runtime.h>

// ---------------------------------------------------------------------------
// LongTermMemoryModule, round 10. FP32 in/out. Changes vs r9:
//  - attn_partial: h <-> XCD affinity. blockIdx round-robins XCDs (bid%8),
//    so bid is remapped to put h in the low 3 bits: all 128 blocks of head h
//    run on XCD h, whose 4MB L2 holds that head's entire 2MB K+V slice.
//    K/V re-reads (the r8/r9 wall: ~0.5-1GB logical from L3) become local
//    L2 hits.
//  - waves own DISJOINT key strips again (r8 interleave, all 64 s-rows per
//    wave): r9's s-half/key-half split made wave pairs load identical K/V
//    strips = 2x VMEM line traffic. Register-P + key-permuted vT kept.
//  - explicit 1-iter K prefetch double buffer (aKA/aKB); V loads issue at
//    iter top, covered by QK MFMA + exp (~240 cy).
//  - proj_fused K/V blocks: mbase <-> XCD remap (bank chunk loaded once
//    into one L2, reused by all 8 heads).
// Shapes: B=32 S=64 D=512 M=8192 H=8 hd=64.
// ---------------------------------------------------------------------------

#define Dm  512
#define Mb  8192
#define BSr 2048

// 0.125 (1/sqrt(hd)) * log2(e): exp2 after pre-scaled QK == softmax exp
#define QSCALE 0.18033688011112042f

typedef float f32x4 __attribute__((ext_vector_type(4)));
typedef short bf16x4 __attribute__((ext_vector_type(4)));
typedef short bf16x8 __attribute__((ext_vector_type(8)));
typedef unsigned short u16x4 __attribute__((ext_vector_type(4)));
typedef unsigned short u16x8 __attribute__((ext_vector_type(8)));
typedef unsigned u32x4 __attribute__((ext_vector_type(4)));

#define MFMA(a, b, c) __builtin_amdgcn_mfma_f32_16x16x32_bf16((a), (b), (c), 0, 0, 0)

#if __has_builtin(__builtin_amdgcn_exp2f)
#define EXP2F(x) __builtin_amdgcn_exp2f(x)
#else
#define EXP2F(x) __expf((x)*0.6931471805599453f)
#endif

__device__ __forceinline__ unsigned short f32_bf16(float f) {
  unsigned u = __builtin_bit_cast(unsigned, f);
  u += 0x7FFFu + ((u >> 16) & 1u);   // RNE
  return (unsigned short)(u >> 16);
}
__device__ __forceinline__ float bf16_f32(unsigned short h) {
  unsigned u = ((unsigned)h) << 16;
  return __builtin_bit_cast(float, u);
}
__device__ __forceinline__ unsigned pack_bf16_trunc(float a, float b) {
  // low half <- bf16(a), high half <- bf16(b); truncation rounding
  return (__builtin_bit_cast(unsigned, a) >> 16) |
         (__builtin_bit_cast(unsigned, b) & 0xFFFF0000u);
}

// ---------------------------------------------------------------------------
// Merged fp32 -> bf16 canonicalization of all 6 tensors (4 elems/thread).
// ---------------------------------------------------------------------------
__global__ __launch_bounds__(256) void convert_all(
    const float* __restrict__ q, const float* __restrict__ bank,
    const float* __restrict__ Win, const float* __restrict__ bin,
    const float* __restrict__ Wout, const float* __restrict__ bout,
    unsigned short* __restrict__ q_c, unsigned short* __restrict__ bank_c,
    unsigned short* __restrict__ Win_c, unsigned short* __restrict__ bin_c,
    unsigned short* __restrict__ Wout_c, unsigned short* __restrict__ bout_c) {
  const int e = (blockIdx.x * 256 + threadIdx.x) * 4;
  const float* src; unsigned short* dst; int off;
  if (e < 1048576)      { src = q;    dst = q_c;    off = e; }
  else if (e < 5242880) { src = bank; dst = bank_c; off = e - 1048576; }
  else if (e < 6029312) { src = Win;  dst = Win_c;  off = e - 5242880; }
  else if (e < 6030848) { src = bin;  dst = bin_c;  off = e - 6029312; }
  else if (e < 6292992) { src = Wout; dst = Wout_c; off = e - 6030848; }
  else                  { src = bout; dst = bout_c; off = e - 6292992; }
  f32x4 v = *(const f32x4*)(src + off);
  u16x4 o;
#pragma unroll
  for (int j = 0; j < 4; ++j) o[j] = f32_bf16(v[j]);
  *(u16x4*)(dst + off) = o;
}

// ---------------------------------------------------------------------------
// Fused projections. Blocks [0,128): Q projection (q_s[bh][s][d], pre-scaled
// by QSCALE). Blocks [128,640): K+V projection (k_s[h][m][d], vT_s[h*64+d][m],
// LDS-staged coalesced stores). vT_s columns are key-permuted inside each
// 32-block: col x holds V[key = (x>>3)*4 + ((x&4)<<2) + (x&3)] so attn's PV
// A-frag (QK C-layout keys qd*4+r over two 16-tiles) matches B-frag qd*8+j.
// K/V block decode is mbase-major in the low bits so the 8 blocks sharing a
// bank chunk (one per h) land on the same XCD (bid%8 round-robin).
// ---------------------------------------------------------------------------
__global__ __launch_bounds__(256) void proj_fused(
    const unsigned short* __restrict__ q_c,
    const unsigned short* __restrict__ bank_c,
    const unsigned short* __restrict__ Win_c,
    const unsigned short* __restrict__ bin_c,
    unsigned short* __restrict__ q_s,
    unsigned short* __restrict__ k_s,
    unsigned short* __restrict__ vT_s) {
  __shared__ __align__(16) unsigned short Kst[128 * 72];
  __shared__ __align__(16) unsigned short Vst[64 * 136];
  const int lane = threadIdx.x & 63;
  const int wv   = threadIdx.x >> 6;
  const int l15  = lane & 15;
  const int qd   = lane >> 4;
  const f32x4 z4 = {0.f, 0.f, 0.f, 0.f};

  if (blockIdx.x < 128) {
    // ---------------- Q projection ----------------
    const int mbase = (blockIdx.x >> 3) * 128 + wv * 32;
    const int nbase = (blockIdx.x & 7) * 64;
    f32x4 acc[2][4];
#pragma unroll
    for (int ti = 0; ti < 2; ++ti)
#pragma unroll
      for (int j = 0; j < 4; ++j) acc[ti][j] = z4;

    const unsigned short* a0p = q_c + (mbase + l15) * Dm + qd * 8;
    const unsigned short* a1p = a0p + 16 * Dm;
    const unsigned short* wp  = Win_c + (nbase + l15) * Dm + qd * 8;

#pragma unroll 4
    for (int k0 = 0; k0 < Dm; k0 += 32) {
      bf16x8 a0 = *(const bf16x8*)(a0p + k0);
      bf16x8 a1 = *(const bf16x8*)(a1p + k0);
#pragma unroll
      for (int j = 0; j < 4; ++j) {
        bf16x8 b = *(const bf16x8*)(wp + j * 16 * Dm + k0);
        acc[0][j] = MFMA(a0, b, acc[0][j]);
        acc[1][j] = MFMA(a1, b, acc[1][j]);
      }
    }
#pragma unroll
    for (int ti = 0; ti < 2; ++ti) {
#pragma unroll
      for (int j = 0; j < 4; ++j) {
        const int n = nbase + j * 16 + l15;
        const float bf = bf16_f32(bin_c[n]);
#pragma unroll
        for (int r = 0; r < 4; ++r) {
          const int m = mbase + ti * 16 + qd * 4 + r;
          const unsigned idx = ((unsigned)(m >> 6) * 8u + (unsigned)(n >> 6)) * 4096u +
                               (unsigned)(m & 63) * 64u + (unsigned)(n & 63);
          q_s[idx] = f32_bf16((acc[ti][j][r] + bf) * QSCALE);
        }
      }
    }
    return;
  }

  // ---------------- K+V projection ----------------
  // mbase-major low bits: XCD = idx%8 groups blocks reading the same bank
  // chunk family; h varies within an XCD so weights+bank chunks stay L2-hot.
  const int idx   = blockIdx.x - 128;
  const int h     = (idx >> 3) & 7;
  const int mbase = ((idx & 7) * 8 + (idx >> 6)) * 128;

  f32x4 kacc[2][4], vacc[2][4];
#pragma unroll
  for (int ti = 0; ti < 2; ++ti)
#pragma unroll
    for (int j = 0; j < 4; ++j) { kacc[ti][j] = z4; vacc[ti][j] = z4; }

  const unsigned short* a0p = bank_c + (mbase + wv * 32 + l15) * Dm + qd * 8;
  const unsigned short* a1p = a0p + 16 * Dm;
  const unsigned short* wkp = Win_c + (Dm + h * 64 + l15) * Dm + qd * 8;
  const unsigned short* wvp = Win_c + (2 * Dm + h * 64 + l15) * Dm + qd * 8;

#pragma unroll 2
  for (int k0 = 0; k0 < Dm; k0 += 32) {
    bf16x8 a0 = *(const bf16x8*)(a0p + k0);
    bf16x8 a1 = *(const bf16x8*)(a1p + k0);
#pragma unroll
    for (int j = 0; j < 4; ++j) {
      bf16x8 wk  = *(const bf16x8*)(wkp + j * 16 * Dm + k0);
      bf16x8 wvv = *(const bf16x8*)(wvp + j * 16 * Dm + k0);
      kacc[0][j] = MFMA(a0, wk, kacc[0][j]);
      kacc[1][j] = MFMA(a1, wk, kacc[1][j]);
      vacc[0][j] = MFMA(a0, wvv, vacc[0][j]);
      vacc[1][j] = MFMA(a1, wvv, vacc[1][j]);
    }
  }

#pragma unroll
  for (int ti = 0; ti < 2; ++ti) {
#pragma unroll
    for (int j = 0; j < 4; ++j) {
      const int d = j * 16 + l15;
      const float bk = bf16_f32(bin_c[Dm + h * 64 + d]);
      const float bv = bf16_f32(bin_c[2 * Dm + h * 64 + d]);
#pragma unroll
      for (int r = 0; r < 4; ++r) {
        const int m = wv * 32 + ti * 16 + qd * 4 + r;
        Kst[m * 72 + d]  = f32_bf16(kacc[ti][j][r] + bk);
        Vst[d * 136 + m] = f32_bf16(vacc[ti][j][r] + bv);
      }
    }
  }
  __syncthreads();

#pragma unroll
  for (int p = 0; p < 4; ++p) {
    const int m = p * 32 + (threadIdx.x >> 3);
    const int d = (threadIdx.x & 7) * 8;
    *(u16x8*)(k_s + h * (Mb * 64) + (mbase + m) * 64 + d) =
        *(const u16x8*)(Kst + m * 72 + d);
  }
  // V copy-out applies the key permutation: dest cols x=m16*8..+7 pull
  // sources {base+q4..+3, base+16+q4..+3}. Two b64 LDS reads, 2-way banked.
#pragma unroll
  for (int p = 0; p < 4; ++p) {
    const int d    = p * 16 + (threadIdx.x >> 4);
    const int m16  = threadIdx.x & 15;
    const int base = (m16 >> 2) * 32;
    const int q4   = (m16 & 3) * 4;
    u16x4 lo = *(const u16x4*)(Vst + d * 136 + base + q4);
    u16x4 hi = *(const u16x4*)(Vst + d * 136 + base + 16 + q4);
    u16x8 o  = __builtin_shufflevector(lo, hi, 0, 1, 2, 3, 4, 5, 6, 7);
    *(u16x8*)(vT_s + (h * 64 + d) * Mb + mbase + m16 * 8) = o;
  }
}

// ---------------------------------------------------------------------------
// Attention partial, S^T formulation, register-resident P, disjoint waves.
// bid = (b*4 + part)*8 + h  ->  all blocks of head h on XCD h (bid%8 RR):
// that head's 2MB K+V slice stays resident in the XCD's 4MB L2.
// Wave wv: all 64 s-rows, keys part*2048 + wv*32 + it*128, it=0..15.
// Per iter: 4 K loads (1-iter prefetched) + 4 V loads (issued at top,
// latency covered by QK+exp), 16 QK MFMA, 32 exp2+pack, 16 PV MFMA.
// No LDS / barriers in the loop.
// ---------------------------------------------------------------------------
__device__ __forceinline__ void load_k(
    const unsigned short* __restrict__ kp, int m0, int l15, int qd,
    bf16x8 aK[4]) {
#pragma unroll
  for (int kt = 0; kt < 2; ++kt)
#pragma unroll
    for (int ks = 0; ks < 2; ++ks)
      aK[kt * 2 + ks] =
          *(const bf16x8*)(kp + (m0 + kt * 16 + l15) * 64 + ks * 32 + qd * 8);
}

__device__ __forceinline__ void attn_step(
    const bf16x8 aK[4], const bf16x8 bQ[4][2],
    const unsigned short* __restrict__ vp, int m0, int l15, int qd,
    f32x4 oacc[4][4], float lsum[4]) {
  // V loads first: ~200cy L2 latency hides under QK MFMA + exp (~240cy)
  bf16x8 bV[4];
#pragma unroll
  for (int dt = 0; dt < 4; ++dt)
    bV[dt] = *(const bf16x8*)(vp + (dt * 16 + l15) * Mb + m0 + qd * 8);

  const f32x4 z4 = {0.f, 0.f, 0.f, 0.f};
  f32x4 sfr[2][4];
#pragma unroll
  for (int kt = 0; kt < 2; ++kt)
#pragma unroll
    for (int sj = 0; sj < 4; ++sj) sfr[kt][sj] = z4;
#pragma unroll
  for (int kt = 0; kt < 2; ++kt)
#pragma unroll
    for (int ks = 0; ks < 2; ++ks)
#pragma unroll
      for (int sj = 0; sj < 4; ++sj)
        sfr[kt][sj] = MFMA(aK[kt * 2 + ks], bQ[sj][ks], sfr[kt][sj]);

  // exp2 + pack: lane's 8 values per sj are the PV A-frag (vT key-permuted)
  bf16x8 aP[4];
#pragma unroll
  for (int sj = 0; sj < 4; ++sj) {
    float e0 = EXP2F(sfr[0][sj][0]), e1 = EXP2F(sfr[0][sj][1]);
    float e2 = EXP2F(sfr[0][sj][2]), e3 = EXP2F(sfr[0][sj][3]);
    float e4 = EXP2F(sfr[1][sj][0]), e5 = EXP2F(sfr[1][sj][1]);
    float e6 = EXP2F(sfr[1][sj][2]), e7 = EXP2F(sfr[1][sj][3]);
    lsum[sj] += ((e0 + e1) + (e2 + e3)) + ((e4 + e5) + (e6 + e7));
    u32x4 pk;
    pk[0] = pack_bf16_trunc(e0, e1);
    pk[1] = pack_bf16_trunc(e2, e3);
    pk[2] = pack_bf16_trunc(e4, e5);
    pk[3] = pack_bf16_trunc(e6, e7);
    aP[sj] = __builtin_bit_cast(bf16x8, pk);
  }

#pragma unroll
  for (int dt = 0; dt < 4; ++dt)
#pragma unroll
    for (int sj = 0; sj < 4; ++sj)
      oacc[sj][dt] = MFMA(aP[sj], bV[dt], oacc[sj][dt]);
}

__global__ __launch_bounds__(256) void attn_partial(
    const unsigned short* __restrict__ q_s,   // [bh][s][d], pre-scaled
    const unsigned short* __restrict__ k_s,   // [h][m][d]
    const unsigned short* __restrict__ vT_s,  // [h][d][m], keyperm'd per 32
    unsigned short* __restrict__ O_part,      // [bh][part][s][d] bf16
    float* __restrict__ l_part) {             // [bh][part][s]
  __shared__ __align__(16) float red[4096];   // 16 KB: cross-wave O reduce
  __shared__ float lred[4][64];

  const int lane = threadIdx.x & 63;
  const int wv   = threadIdx.x >> 6;
  const int l15  = lane & 15;
  const int qd   = lane >> 4;
  const int h    = blockIdx.x & 7;          // XCD = bid % 8 == h
  const int part = (blockIdx.x >> 3) & 3;
  const int b    = blockIdx.x >> 5;
  const int bh   = b * 8 + h;

  const unsigned short* qp = q_s + bh * 4096;
  const unsigned short* kp = k_s + h * (Mb * 64);
  const unsigned short* vp = vT_s + h * (Mb * 64);

  // Q as B-operand: B[k=d][n=s], n = l15 -> rows sj*16 + l15
  bf16x8 bQ[4][2];
#pragma unroll
  for (int sj = 0; sj < 4; ++sj)
#pragma unroll
    for (int ks = 0; ks < 2; ++ks)
      bQ[sj][ks] = *(const bf16x8*)(qp + (sj * 16 + l15) * 64 + ks * 32 + qd * 8);

  const f32x4 z4 = {0.f, 0.f, 0.f, 0.f};
  f32x4 oacc[4][4];
  float lsum[4] = {0.f, 0.f, 0.f, 0.f};
#pragma unroll
  for (int sj = 0; sj < 4; ++sj)
#pragma unroll
    for (int dt = 0; dt < 4; ++dt) oacc[sj][dt] = z4;

  const int mwv = part * 2048 + wv * 32;

  bf16x8 aKA[4], aKB[4];
  load_k(kp, mwv, l15, qd, aKA);
  for (int p = 0; p < 7; ++p) {
    load_k(kp, mwv + (2 * p + 1) * 128, l15, qd, aKB);
    attn_step(aKA, bQ, vp, mwv + (2 * p) * 128, l15, qd, oacc, lsum);
    load_k(kp, mwv + (2 * p + 2) * 128, l15, qd, aKA);
    attn_step(aKB, bQ, vp, mwv + (2 * p + 1) * 128, l15, qd, oacc, lsum);
  }
  load_k(kp, mwv + 15 * 128, l15, qd, aKB);
  attn_step(aKA, bQ, vp, mwv + 14 * 128, l15, qd, oacc, lsum);
  attn_step(aKB, bQ, vp, mwv + 15 * 128, l15, qd, oacc, lsum);

  // --- l: lane holds partial for s = sj*16+l15 over its keys; reduce quads ---
#pragma unroll
  for (int sj = 0; sj < 4; ++sj) {
    float v = lsum[sj];
    v += __shfl_xor(v, 16);
    v += __shfl_xor(v, 32);
    if (qd == 0) lred[wv][sj * 16 + l15] = v;
  }
  __syncthreads();
  if (threadIdx.x < 64)
    l_part[(bh * 4 + part) * 64 + threadIdx.x] =
        lred[0][threadIdx.x] + lred[1][threadIdx.x] +
        lred[2][threadIdx.x] + lred[3][threadIdx.x];

  // --- O: reduce across waves in 4 chunks, store bf16 ---
  unsigned short* Ob = O_part + (bh * 4 + part) * 4096;
  for (int ti = 0; ti < 4; ++ti) {
    __syncthreads();
#pragma unroll
    for (int dt = 0; dt < 4; ++dt)
#pragma unroll
      for (int r = 0; r < 4; ++r)
        red[wv * 1024 + dt * 256 + r * 64 + lane] = oacc[ti][dt][r];
    __syncthreads();
#pragma unroll
    for (int j = 0; j < 4; ++j) {
      const int idx = j * 256 + threadIdx.x;
      const float s = red[idx] + red[1024 + idx] + red[2048 + idx] + red[3072 + idx];
      const int ln = idx & 63;
      const int r  = (idx >> 6) & 3;
      const int dt = idx >> 8;
      const int srow = ti * 16 + (ln >> 4) * 4 + r;
      const int dcol = dt * 16 + (ln & 15);
      Ob[srow * 64 + dcol] = f32_bf16(s);
    }
  }
}

// ---------------------------------------------------------------------------
// Fused: blocks [0,1024) combine attention partials -> a_stage bf16;
// blocks [1024,5120) write new_bank fp32 (overwrites the K/V scratch).
// Both depend only on attn_partial; disjoint memory.
// ---------------------------------------------------------------------------
__global__ __launch_bounds__(256) void combine_bank(
    const unsigned short* __restrict__ O_part, const float* __restrict__ l_part,
    unsigned short* __restrict__ a_stage,
    const float* __restrict__ memory, const float* __restrict__ bank,
    const int* __restrict__ ptrp, float* __restrict__ out_bank) {
  if (blockIdx.x < 1024) {
    const int e  = (blockIdx.x * 256 + threadIdx.x) * 4;  // < 1048576
    const int bh = e >> 12;
    const int rem = e & 4095;
    const int s  = rem >> 6;
    const int d  = rem & 63;
    float acc[4] = {0.f, 0.f, 0.f, 0.f};
    float l = 0.f;
#pragma unroll
    for (int p = 0; p < 4; ++p) {
      u16x4 v = *(const u16x4*)(O_part + (bh * 4 + p) * 4096 + rem);
#pragma unroll
      for (int j = 0; j < 4; ++j) acc[j] += bf16_f32(v[j]);
      l += l_part[(bh * 4 + p) * 64 + s];
    }
    const int b = bh >> 3, h = bh & 7;
    u16x4 o;
#pragma unroll
    for (int j = 0; j < 4; ++j) o[j] = f32_bf16(acc[j] / l);
    *(u16x4*)(a_stage + (b * 64 + s) * 512 + h * 64 + d) = o;
  } else {
    const int t  = (blockIdx.x - 1024) * 256 + threadIdx.x;  // < 1,048,576
    const int r  = t >> 7;
    const int c4 = (t & 127) * 4;
    const int ptr = ptrp[0];
    const unsigned off = (unsigned)(r - ptr + Mb) & (Mb - 1);
    const float* src = (off < (unsigned)BSr) ? memory + off * Dm + c4
                                             : bank + r * Dm + c4;
    *(f32x4*)(out_bank + r * Dm + c4) = *(const f32x4*)src;
  }
}

// ---------------------------------------------------------------------------
// retrieved[m,n] = a_stage[m,:] @ Wout[n,:] + bout[n]  -> fp32 d_out.
// ---------------------------------------------------------------------------
__global__ __launch_bounds__(256) void out_proj(
    const unsigned short* __restrict__ A,
    const unsigned short* __restrict__ W,
    const unsigned short* __restrict__ bias,
    float* __restrict__ out) {
  const int lane = threadIdx.x & 63;
  const int wv   = threadIdx.x >> 6;
  const int l15  = lane & 15;
  const int qd   = lane >> 4;
  const int mbase = blockIdx.y * 128 + wv * 32;
  const int nbase = blockIdx.x * 64;

  const f32x4 z4 = {0.f, 0.f, 0.f, 0.f};
  f32x4 acc[2][4];
#pragma unroll
  for (int ti = 0; ti < 2; ++ti)
#pragma unroll
    for (int j = 0; j < 4; ++j) acc[ti][j] = z4;

  const unsigned short* a0p = A + (mbase + l15) * Dm + qd * 8;
  const unsigned short* a1p = a0p + 16 * Dm;
  const unsigned short* wp  = W + (nbase + l15) * Dm + qd * 8;

#pragma unroll 4
  for (int k0 = 0; k0 < Dm; k0 += 32) {
    bf16x8 a0 = *(const bf16x8*)(a0p + k0);
    bf16x8 a1 = *(const bf16x8*)(a1p + k0);
#pragma unroll
    for (int j = 0; j < 4; ++j) {
      bf16x8 bfr = *(const bf16x8*)(wp + j * 16 * Dm + k0);
      acc[0][j] = MFMA(a0, bfr, acc[0][j]);
      acc[1][j] = MFMA(a1, bfr, acc[1][j]);
    }
  }

#pragma unroll
  for (int ti = 0; ti < 2; ++ti) {
#pragma unroll
    for (int j = 0; j < 4; ++j) {
      const int n = nbase + j * 16 + l15;
      const float bf = bf16_f32(bias[n]);
#pragma unroll
      for (int r = 0; r < 4; ++r) {
        const int m = mbase + ti * 16 + qd * 4 + r;
        out[m * Dm + n] = acc[ti][j][r] + bf;
      }
    }
  }
}

// ---------------------------------------------------------------------------
extern "C" void kernel_launch(void* const* d_in, const int* in_sizes, int n_in,
                              void* d_out, int out_size, void* d_ws, size_t ws_size,
                              hipStream_t stream) {
  const float* query = (const float*)d_in[0];
  const float* memry = (const float*)d_in[1];
  const float* bank  = (const float*)d_in[2];
  const float* Win   = (const float*)d_in[3];
  const float* bin   = (const float*)d_in[4];
  const float* Wout  = (const float*)d_in[5];
  const float* bout  = (const float*)d_in[6];
  const int*   ptrp  = (const int*)d_in[7];
  float* outf = (float*)d_out;

  // ws layout (14.3 MB; 15.8 MB proven). Lifetime-disjoint aliases:
  // a_stage reuses q_c; O_part reuses bank_c.
  char* ws = (char*)d_ws;
  unsigned short* q_c     = (unsigned short*)(ws);                 //  0 ..  2 MB
  unsigned short* a_stage = (unsigned short*)(ws);                 //  (alias)
  unsigned short* bank_c  = (unsigned short*)(ws + (2u << 20));    //  2 .. 10 MB
  unsigned short* O_part  = (unsigned short*)(ws + (2u << 20));    //  (alias)
  unsigned short* Win_c   = (unsigned short*)(ws + (10u << 20));   // 10 .. 11.5 MB
  unsigned short* Wout_c  = (unsigned short*)(ws + 12058624u);     // 11.5 .. 12 MB
  unsigned short* q_s     = (unsigned short*)(ws + (12u << 20));   // 12 .. 14 MB
  float*          l_part  = (float*)(ws + (14u << 20));            // 14 .. 14.25 MB
  unsigned short* bin_c   = (unsigned short*)(ws + 14942208u);
  unsigned short* bout_c  = (unsigned short*)(ws + 14945280u);

  // K/V scratch in d_out's bank region; combine_bank rewrites it afterwards.
  unsigned short* kv = (unsigned short*)(outf + 1048576);
  unsigned short* k_s  = kv;             // 8 MB: [h][m][d]
  unsigned short* vT_s = kv + 4194304;   // 8 MB: [h][d][m] (keyperm'd)

  convert_all<<<6146, 256, 0, stream>>>(query, bank, Win, bin, Wout, bout,
                                        q_c, bank_c, Win_c, bin_c, Wout_c, bout_c);

  proj_fused<<<640, 256, 0, stream>>>(q_c, bank_c, Win_c, bin_c, q_s, k_s, vT_s);

  attn_partial<<<1024, 256, 0, stream>>>(q_s, k_s, vT_s, O_part, l_part);

  combine_bank<<<5120, 256, 0, stream>>>(O_part, l_part, a_stage,
                                         memry, bank, ptrp, outf + 1048576);

  out_proj<<<dim3(8, 16), 256, 0, stream>>>(a_stage, Wout_c, bout_c, outf);
}

// Round 3
// 197.640 us; speedup vs baseline: 1.4275x; 1.2032x over previous
//
#include <hip/hip_runtime.h>

// ---------------------------------------------------------------------------
// LongTermMemoryModule, round 11. FP32 in/out. Changes vs r10:
//  - attn_partial rebuilt on the T3 2-phase template: K/V strips (128 keys)
//    staged to LDS via __builtin_amdgcn_global_load_lds (async DMA, no VGPR
//    landing), double-buffered, ONE vmcnt(0)+barrier per strip. r8/r10 both
//    hit an 81us wall because PV consumed the newest loads -> vmcnt(0) every
//    iter -> no loads in flight across iterations.
//  - all 4 waves share the staged strip: waves split (batch x s-half), 2
//    batches per block -> per-CU L2 traffic halved, oacc 16 regs/s-tile.
//  - T2 bank swizzle: K rows (128B) and V rows (256B) are stride=0 mod 32
//    banks; ds_read_b128 runs 2x the floor. XOR col^=(row&7)<<4 applied at
//    GLOBAL WRITE time in proj_fused (linear DMA dest + pre-swizzled source
//    + swizzled read) -> b128 floor rate.
//  - grid 512 = (bp,part,h): h in low 3 bits keeps the h<->XCD pinning.
// Shapes: B=32 S=64 D=512 M=8192 H=8 hd=64.
// ---------------------------------------------------------------------------

#define Dm  512
#define Mb  8192
#define BSr 2048

// 0.125 (1/sqrt(hd)) * log2(e): exp2 after pre-scaled QK == softmax exp
#define QSCALE 0.18033688011112042f

typedef float f32x4 __attribute__((ext_vector_type(4)));
typedef short bf16x4 __attribute__((ext_vector_type(4)));
typedef short bf16x8 __attribute__((ext_vector_type(8)));
typedef unsigned short u16x4 __attribute__((ext_vector_type(4)));
typedef unsigned short u16x8 __attribute__((ext_vector_type(8)));
typedef unsigned u32x4 __attribute__((ext_vector_type(4)));

#define MFMA(a, b, c) __builtin_amdgcn_mfma_f32_16x16x32_bf16((a), (b), (c), 0, 0, 0)

#if __has_builtin(__builtin_amdgcn_exp2f)
#define EXP2F(x) __builtin_amdgcn_exp2f(x)
#else
#define EXP2F(x) __expf((x)*0.6931471805599453f)
#endif

__device__ __forceinline__ unsigned short f32_bf16(float f) {
  unsigned u = __builtin_bit_cast(unsigned, f);
  u += 0x7FFFu + ((u >> 16) & 1u);   // RNE
  return (unsigned short)(u >> 16);
}
__device__ __forceinline__ float bf16_f32(unsigned short h) {
  unsigned u = ((unsigned)h) << 16;
  return __builtin_bit_cast(float, u);
}
__device__ __forceinline__ unsigned pack_bf16_trunc(float a, float b) {
  // low half <- bf16(a), high half <- bf16(b); truncation rounding
  return (__builtin_bit_cast(unsigned, a) >> 16) |
         (__builtin_bit_cast(unsigned, b) & 0xFFFF0000u);
}

// async global(16B/lane) -> LDS(wave-uniform base + lane*16)
__device__ __forceinline__ void gload16(const unsigned short* g, unsigned short* l) {
  __builtin_amdgcn_global_load_lds(
      (const __attribute__((address_space(1))) void*)g,
      (__attribute__((address_space(3))) void*)l, 16, 0, 0);
}

// ---------------------------------------------------------------------------
// Merged fp32 -> bf16 canonicalization of all 6 tensors (4 elems/thread).
// ---------------------------------------------------------------------------
__global__ __launch_bounds__(256) void convert_all(
    const float* __restrict__ q, const float* __restrict__ bank,
    const float* __restrict__ Win, const float* __restrict__ bin,
    const float* __restrict__ Wout, const float* __restrict__ bout,
    unsigned short* __restrict__ q_c, unsigned short* __restrict__ bank_c,
    unsigned short* __restrict__ Win_c, unsigned short* __restrict__ bin_c,
    unsigned short* __restrict__ Wout_c, unsigned short* __restrict__ bout_c) {
  const int e = (blockIdx.x * 256 + threadIdx.x) * 4;
  const float* src; unsigned short* dst; int off;
  if (e < 1048576)      { src = q;    dst = q_c;    off = e; }
  else if (e < 5242880) { src = bank; dst = bank_c; off = e - 1048576; }
  else if (e < 6029312) { src = Win;  dst = Win_c;  off = e - 5242880; }
  else if (e < 6030848) { src = bin;  dst = bin_c;  off = e - 6029312; }
  else if (e < 6292992) { src = Wout; dst = Wout_c; off = e - 6030848; }
  else                  { src = bout; dst = bout_c; off = e - 6292992; }
  f32x4 v = *(const f32x4*)(src + off);
  u16x4 o;
#pragma unroll
  for (int j = 0; j < 4; ++j) o[j] = f32_bf16(v[j]);
  *(u16x4*)(dst + off) = o;
}

// ---------------------------------------------------------------------------
// Fused projections. Blocks [0,128): Q projection (q_s[bh][s][d], pre-scaled
// by QSCALE). Blocks [128,640): K+V projection (k_s[h][m][d] bank-swizzled,
// vT_s[h*64+d][m] key-permuted + bank-swizzled, LDS-staged coalesced stores).
// Key permutation (per 32-block): col x holds V[key=(x>>3)*4+((x&4)<<2)+(x&3)]
// so attn's PV A-frag (QK C-layout) matches the B-frag slots.
// Bank swizzle (T2): 16B chunk of logical col C in row r stored at
// C ^ ((r&7)<<4); attn reads with the same XOR (involution).
// ---------------------------------------------------------------------------
__global__ __launch_bounds__(256) void proj_fused(
    const unsigned short* __restrict__ q_c,
    const unsigned short* __restrict__ bank_c,
    const unsigned short* __restrict__ Win_c,
    const unsigned short* __restrict__ bin_c,
    unsigned short* __restrict__ q_s,
    unsigned short* __restrict__ k_s,
    unsigned short* __restrict__ vT_s) {
  __shared__ __align__(16) unsigned short Kst[128 * 72];
  __shared__ __align__(16) unsigned short Vst[64 * 136];
  const int lane = threadIdx.x & 63;
  const int wv   = threadIdx.x >> 6;
  const int l15  = lane & 15;
  const int qd   = lane >> 4;
  const f32x4 z4 = {0.f, 0.f, 0.f, 0.f};

  if (blockIdx.x < 128) {
    // ---------------- Q projection ----------------
    const int mbase = (blockIdx.x >> 3) * 128 + wv * 32;
    const int nbase = (blockIdx.x & 7) * 64;
    f32x4 acc[2][4];
#pragma unroll
    for (int ti = 0; ti < 2; ++ti)
#pragma unroll
      for (int j = 0; j < 4; ++j) acc[ti][j] = z4;

    const unsigned short* a0p = q_c + (mbase + l15) * Dm + qd * 8;
    const unsigned short* a1p = a0p + 16 * Dm;
    const unsigned short* wp  = Win_c + (nbase + l15) * Dm + qd * 8;

#pragma unroll 4
    for (int k0 = 0; k0 < Dm; k0 += 32) {
      bf16x8 a0 = *(const bf16x8*)(a0p + k0);
      bf16x8 a1 = *(const bf16x8*)(a1p + k0);
#pragma unroll
      for (int j = 0; j < 4; ++j) {
        bf16x8 b = *(const bf16x8*)(wp + j * 16 * Dm + k0);
        acc[0][j] = MFMA(a0, b, acc[0][j]);
        acc[1][j] = MFMA(a1, b, acc[1][j]);
      }
    }
#pragma unroll
    for (int ti = 0; ti < 2; ++ti) {
#pragma unroll
      for (int j = 0; j < 4; ++j) {
        const int n = nbase + j * 16 + l15;
        const float bf = bf16_f32(bin_c[n]);
#pragma unroll
        for (int r = 0; r < 4; ++r) {
          const int m = mbase + ti * 16 + qd * 4 + r;
          const unsigned idx = ((unsigned)(m >> 6) * 8u + (unsigned)(n >> 6)) * 4096u +
                               (unsigned)(m & 63) * 64u + (unsigned)(n & 63);
          q_s[idx] = f32_bf16((acc[ti][j][r] + bf) * QSCALE);
        }
      }
    }
    return;
  }

  // ---------------- K+V projection ----------------
  const int idx   = blockIdx.x - 128;
  const int h     = (idx >> 3) & 7;
  const int mbase = ((idx & 7) * 8 + (idx >> 6)) * 128;

  f32x4 kacc[2][4], vacc[2][4];
#pragma unroll
  for (int ti = 0; ti < 2; ++ti)
#pragma unroll
    for (int j = 0; j < 4; ++j) { kacc[ti][j] = z4; vacc[ti][j] = z4; }

  const unsigned short* a0p = bank_c + (mbase + wv * 32 + l15) * Dm + qd * 8;
  const unsigned short* a1p = a0p + 16 * Dm;
  const unsigned short* wkp = Win_c + (Dm + h * 64 + l15) * Dm + qd * 8;
  const unsigned short* wvp = Win_c + (2 * Dm + h * 64 + l15) * Dm + qd * 8;

#pragma unroll 2
  for (int k0 = 0; k0 < Dm; k0 += 32) {
    bf16x8 a0 = *(const bf16x8*)(a0p + k0);
    bf16x8 a1 = *(const bf16x8*)(a1p + k0);
#pragma unroll
    for (int j = 0; j < 4; ++j) {
      bf16x8 wk  = *(const bf16x8*)(wkp + j * 16 * Dm + k0);
      bf16x8 wvv = *(const bf16x8*)(wvp + j * 16 * Dm + k0);
      kacc[0][j] = MFMA(a0, wk, kacc[0][j]);
      kacc[1][j] = MFMA(a1, wk, kacc[1][j]);
      vacc[0][j] = MFMA(a0, wvv, vacc[0][j]);
      vacc[1][j] = MFMA(a1, wvv, vacc[1][j]);
    }
  }

#pragma unroll
  for (int ti = 0; ti < 2; ++ti) {
#pragma unroll
    for (int j = 0; j < 4; ++j) {
      const int d = j * 16 + l15;
      const float bk = bf16_f32(bin_c[Dm + h * 64 + d]);
      const float bv = bf16_f32(bin_c[2 * Dm + h * 64 + d]);
#pragma unroll
      for (int r = 0; r < 4; ++r) {
        const int m = wv * 32 + ti * 16 + qd * 4 + r;
        Kst[m * 72 + d]  = f32_bf16(kacc[ti][j][r] + bk);
        Vst[d * 136 + m] = f32_bf16(vacc[ti][j][r] + bv);
      }
    }
  }
  __syncthreads();

  // K copy-out: logical 16B chunk (key m, d-cols c8*8..+7) stored bank-swizzled
#pragma unroll
  for (int p = 0; p < 4; ++p) {
    const int m  = p * 32 + (threadIdx.x >> 3);
    const int c8 = threadIdx.x & 7;                 // logical 16B chunk index
    const int d  = c8 * 8;
    *(u16x8*)(k_s + h * (Mb * 64) + (mbase + m) * 64 + ((c8 ^ (m & 7)) * 8)) =
        *(const u16x8*)(Kst + m * 72 + d);
  }
  // V copy-out: key permutation in the SOURCE gather, bank swizzle in the
  // DEST address (both involutions; attn reads with the same XOR).
#pragma unroll
  for (int p = 0; p < 4; ++p) {
    const int d    = p * 16 + (threadIdx.x >> 4);
    const int m16  = threadIdx.x & 15;              // logical 16B chunk index
    const int base = (m16 >> 2) * 32;
    const int q4   = (m16 & 3) * 4;
    u16x4 lo = *(const u16x4*)(Vst + d * 136 + base + q4);
    u16x4 hi = *(const u16x4*)(Vst + d * 136 + base + 16 + q4);
    u16x8 o  = __builtin_shufflevector(lo, hi, 0, 1, 2, 3, 4, 5, 6, 7);
    *(u16x8*)(vT_s + (h * 64 + d) * Mb + mbase + ((m16 ^ (d & 7)) * 8)) = o;
  }
}

// ---------------------------------------------------------------------------
// Attention partial, 2-phase LDS-staged. Block = (bp, part, h), 512 blocks,
// h = bid&7 -> XCD pinning. Waves: wv>>1 = batch (bp*2+{0,1}), wv&1 = s-half
// (32 rows). 16 strips of 128 keys; K strip 16KB + V strip 16KB staged via
// global_load_lds, double-buffered (64KB LDS, 2 blocks/CU). One vmcnt(0) +
// barrier per strip: staging for strip t+1 flies under strip t's compute.
// ds_reads hit the b128 floor via the (row&7)<<4 XOR pre-applied in global.
// ---------------------------------------------------------------------------
__global__ __launch_bounds__(256, 2) void attn_partial(
    const unsigned short* __restrict__ q_s,   // [bh][s][d], pre-scaled
    const unsigned short* __restrict__ k_s,   // [h][m][d] swizzled
    const unsigned short* __restrict__ vT_s,  // [h][d][m] keyperm+swizzled
    unsigned short* __restrict__ O_part,      // [bh][part][s][d] bf16
    float* __restrict__ l_part) {             // [bh][part][s]
  __shared__ __align__(16) unsigned short Kbuf[2][128 * 64];  // 2 x 16 KB
  __shared__ __align__(16) unsigned short Vbuf[2][64 * 128];  // 2 x 16 KB

  const int lane = threadIdx.x & 63;
  const int wv   = threadIdx.x >> 6;
  const int l15  = lane & 15;
  const int qd   = lane >> 4;
  const int h    = blockIdx.x & 7;            // XCD = bid % 8 == h
  const int g    = blockIdx.x >> 3;
  const int part = g & 3;
  const int b    = (g >> 2) * 2 + (wv >> 1);
  const int bh   = b * 8 + h;
  const int s0   = (wv & 1) * 32;

  const unsigned short* kp = k_s  + h * (Mb * 64);
  const unsigned short* vp = vT_s + h * (Mb * 64);
  const int m0p = part * 2048;

  // Q as B-operand: B[k=d][n=s], n = l15 -> rows s0 + sj*16 + l15
  bf16x8 bQ[2][2];
  {
    const unsigned short* qp = q_s + bh * 4096;
#pragma unroll
    for (int sj = 0; sj < 2; ++sj)
#pragma unroll
      for (int ks = 0; ks < 2; ++ks)
        bQ[sj][ks] = *(const bf16x8*)(qp + (s0 + sj * 16 + l15) * 64 + ks * 32 + qd * 8);
  }

  const f32x4 z4 = {0.f, 0.f, 0.f, 0.f};
  f32x4 oacc[2][4];
  float lsum[2] = {0.f, 0.f};
#pragma unroll
  for (int sj = 0; sj < 2; ++sj)
#pragma unroll
    for (int dt = 0; dt < 4; ++dt) oacc[sj][dt] = z4;

  const int swz = (l15 & 7) * 8;  // u16-unit XOR (== byte (l15&7)<<4)

  // --- staging: wave wv copies keys [wv*32,+32) and d-rows [wv*16,+16) ---
  auto stage = [&](int buf, int m0) {
    const unsigned short* gk = kp + (m0 + wv * 32 + (lane >> 3)) * 64 + (lane & 7) * 8;
    unsigned short* lk = &Kbuf[buf][(wv * 32) * 64];
#pragma unroll
    for (int i = 0; i < 4; ++i) gload16(gk + i * 8 * 64, lk + i * 8 * 64);
    const unsigned short* gv = vp + (wv * 16 + (lane >> 4)) * Mb + m0 + (lane & 15) * 8;
    unsigned short* lv = &Vbuf[buf][(wv * 16) * 128];
#pragma unroll
    for (int i = 0; i < 4; ++i) gload16(gv + i * 4 * Mb, lv + i * 4 * 128);
  };

  // --- compute one 128-key strip from LDS ---
  auto compute = [&](int buf) {
    const unsigned short* Kb = Kbuf[buf];
    const unsigned short* Vb = Vbuf[buf];
#pragma unroll
    for (int c2 = 0; c2 < 2; ++c2) {  // 64-key halves
      f32x4 sfr[4][2];
#pragma unroll
      for (int kt = 0; kt < 4; ++kt)
#pragma unroll
        for (int sj = 0; sj < 2; ++sj) sfr[kt][sj] = z4;
#pragma unroll
      for (int kt = 0; kt < 4; ++kt) {
        const int row = c2 * 64 + kt * 16 + l15;
#pragma unroll
        for (int ks = 0; ks < 2; ++ks) {
          bf16x8 aK = *(const bf16x8*)(Kb + row * 64 + ((ks * 32 + qd * 8) ^ swz));
#pragma unroll
          for (int sj = 0; sj < 2; ++sj)
            sfr[kt][sj] = MFMA(aK, bQ[sj][ks], sfr[kt][sj]);
        }
      }
      // exp2 + pack: lane's 8 values per (sj, 32-key chunk) are the PV A-frag
      bf16x8 aP[2][2];
#pragma unroll
      for (int sj = 0; sj < 2; ++sj) {
#pragma unroll
        for (int c = 0; c < 2; ++c) {
          const f32x4 lo = sfr[c * 2][sj];
          const f32x4 hi = sfr[c * 2 + 1][sj];
          float e0 = EXP2F(lo[0]), e1 = EXP2F(lo[1]);
          float e2 = EXP2F(lo[2]), e3 = EXP2F(lo[3]);
          float e4 = EXP2F(hi[0]), e5 = EXP2F(hi[1]);
          float e6 = EXP2F(hi[2]), e7 = EXP2F(hi[3]);
          lsum[sj] += ((e0 + e1) + (e2 + e3)) + ((e4 + e5) + (e6 + e7));
          u32x4 pk;
          pk[0] = pack_bf16_trunc(e0, e1);
          pk[1] = pack_bf16_trunc(e2, e3);
          pk[2] = pack_bf16_trunc(e4, e5);
          pk[3] = pack_bf16_trunc(e6, e7);
          aP[sj][c] = __builtin_bit_cast(bf16x8, pk);
        }
      }
      // PV
#pragma unroll
      for (int c = 0; c < 2; ++c) {
#pragma unroll
        for (int dt = 0; dt < 4; ++dt) {
          const int d = dt * 16 + l15;
          bf16x8 bV = *(const bf16x8*)(Vb + d * 128 + ((c2 * 64 + c * 32 + qd * 8) ^ swz));
#pragma unroll
          for (int sj = 0; sj < 2; ++sj)
            oacc[sj][dt] = MFMA(aP[sj][c], bV, oacc[sj][dt]);
        }
      }
    }
  };

  // --- 2-phase main loop ---
  stage(0, m0p);
  __asm__ volatile("s_waitcnt vmcnt(0)" ::: "memory");
  __syncthreads();
#pragma unroll 1
  for (int t = 0; t < 15; ++t) {
    stage((t + 1) & 1, m0p + (t + 1) * 128);
    compute(t & 1);
    __asm__ volatile("s_waitcnt vmcnt(0)" ::: "memory");
    __syncthreads();
  }
  compute(1);

  // --- l: lane holds partial for s = s0 + sj*16 + l15; reduce over qd ---
#pragma unroll
  for (int sj = 0; sj < 2; ++sj) {
    float v = lsum[sj];
    v += __shfl_xor(v, 16);
    v += __shfl_xor(v, 32);
    if (qd == 0) l_part[(bh * 4 + part) * 64 + s0 + sj * 16 + l15] = v;
  }

  // --- O: lane holds O[s = s0+sj*16+qd*4+r][d = dt*16+l15]; direct store ---
  unsigned short* Ob = O_part + (bh * 4 + part) * 4096;
#pragma unroll
  for (int sj = 0; sj < 2; ++sj)
#pragma unroll
    for (int dt = 0; dt < 4; ++dt)
#pragma unroll
      for (int r = 0; r < 4; ++r)
        Ob[(s0 + sj * 16 + qd * 4 + r) * 64 + dt * 16 + l15] = f32_bf16(oacc[sj][dt][r]);
}

// ---------------------------------------------------------------------------
// Fused: blocks [0,1024) combine attention partials -> a_stage bf16;
// blocks [1024,5120) write new_bank fp32 (overwrites the K/V scratch).
// Both depend only on attn_partial; disjoint memory.
// ---------------------------------------------------------------------------
__global__ __launch_bounds__(256) void combine_bank(
    const unsigned short* __restrict__ O_part, const float* __restrict__ l_part,
    unsigned short* __restrict__ a_stage,
    const float* __restrict__ memory, const float* __restrict__ bank,
    const int* __restrict__ ptrp, float* __restrict__ out_bank) {
  if (blockIdx.x < 1024) {
    const int e  = (blockIdx.x * 256 + threadIdx.x) * 4;  // < 1048576
    const int bh = e >> 12;
    const int rem = e & 4095;
    const int s  = rem >> 6;
    const int d  = rem & 63;
    float acc[4] = {0.f, 0.f, 0.f, 0.f};
    float l = 0.f;
#pragma unroll
    for (int p = 0; p < 4; ++p) {
      u16x4 v = *(const u16x4*)(O_part + (bh * 4 + p) * 4096 + rem);
#pragma unroll
      for (int j = 0; j < 4; ++j) acc[j] += bf16_f32(v[j]);
      l += l_part[(bh * 4 + p) * 64 + s];
    }
    const int b = bh >> 3, h = bh & 7;
    u16x4 o;
#pragma unroll
    for (int j = 0; j < 4; ++j) o[j] = f32_bf16(acc[j] / l);
    *(u16x4*)(a_stage + (b * 64 + s) * 512 + h * 64 + d) = o;
  } else {
    const int t  = (blockIdx.x - 1024) * 256 + threadIdx.x;  // < 1,048,576
    const int r  = t >> 7;
    const int c4 = (t & 127) * 4;
    const int ptr = ptrp[0];
    const unsigned off = (unsigned)(r - ptr + Mb) & (Mb - 1);
    const float* src = (off < (unsigned)BSr) ? memory + off * Dm + c4
                                             : bank + r * Dm + c4;
    *(f32x4*)(out_bank + r * Dm + c4) = *(const f32x4*)src;
  }
}

// ---------------------------------------------------------------------------
// retrieved[m,n] = a_stage[m,:] @ Wout[n,:] + bout[n]  -> fp32 d_out.
// ---------------------------------------------------------------------------
__global__ __launch_bounds__(256) void out_proj(
    const unsigned short* __restrict__ A,
    const unsigned short* __restrict__ W,
    const unsigned short* __restrict__ bias,
    float* __restrict__ out) {
  const int lane = threadIdx.x & 63;
  const int wv   = threadIdx.x >> 6;
  const int l15  = lane & 15;
  const int qd   = lane >> 4;
  const int mbase = blockIdx.y * 128 + wv * 32;
  const int nbase = blockIdx.x * 64;

  const f32x4 z4 = {0.f, 0.f, 0.f, 0.f};
  f32x4 acc[2][4];
#pragma unroll
  for (int ti = 0; ti < 2; ++ti)
#pragma unroll
    for (int j = 0; j < 4; ++j) acc[ti][j] = z4;

  const unsigned short* a0p = A + (mbase + l15) * Dm + qd * 8;
  const unsigned short* a1p = a0p + 16 * Dm;
  const unsigned short* wp  = W + (nbase + l15) * Dm + qd * 8;

#pragma unroll 4
  for (int k0 = 0; k0 < Dm; k0 += 32) {
    bf16x8 a0 = *(const bf16x8*)(a0p + k0);
    bf16x8 a1 = *(const bf16x8*)(a1p + k0);
#pragma unroll
    for (int j = 0; j < 4; ++j) {
      bf16x8 bfr = *(const bf16x8*)(wp + j * 16 * Dm + k0);
      acc[0][j] = MFMA(a0, bfr, acc[0][j]);
      acc[1][j] = MFMA(a1, bfr, acc[1][j]);
    }
  }

#pragma unroll
  for (int ti = 0; ti < 2; ++ti) {
#pragma unroll
    for (int j = 0; j < 4; ++j) {
      const int n = nbase + j * 16 + l15;
      const float bf = bf16_f32(bias[n]);
#pragma unroll
      for (int r = 0; r < 4; ++r) {
        const int m = mbase + ti * 16 + qd * 4 + r;
        out[m * Dm + n] = acc[ti][j][r] + bf;
      }
    }
  }
}

// ---------------------------------------------------------------------------
extern "C" void kernel_launch(void* const* d_in, const int* in_sizes, int n_in,
                              void* d_out, int out_size, void* d_ws, size_t ws_size,
                              hipStream_t stream) {
  const float* query = (const float*)d_in[0];
  const float* memry = (const float*)d_in[1];
  const float* bank  = (const float*)d_in[2];
  const float* Win   = (const float*)d_in[3];
  const float* bin   = (const float*)d_in[4];
  const float* Wout  = (const float*)d_in[5];
  const float* bout  = (const float*)d_in[6];
  const int*   ptrp  = (const int*)d_in[7];
  float* outf = (float*)d_out;

  // ws layout (14.3 MB; 15.8 MB proven). Lifetime-disjoint aliases:
  // a_stage reuses q_c; O_part reuses bank_c.
  char* ws = (char*)d_ws;
  unsigned short* q_c     = (unsigned short*)(ws);                 //  0 ..  2 MB
  unsigned short* a_stage = (unsigned short*)(ws);                 //  (alias)
  unsigned short* bank_c  = (unsigned short*)(ws + (2u << 20));    //  2 .. 10 MB
  unsigned short* O_part  = (unsigned short*)(ws + (2u << 20));    //  (alias)
  unsigned short* Win_c   = (unsigned short*)(ws + (10u << 20));   // 10 .. 11.5 MB
  unsigned short* Wout_c  = (unsigned short*)(ws + 12058624u);     // 11.5 .. 12 MB
  unsigned short* q_s     = (unsigned short*)(ws + (12u << 20));   // 12 .. 14 MB
  float*          l_part  = (float*)(ws + (14u << 20));            // 14 .. 14.25 MB
  unsigned short* bin_c   = (unsigned short*)(ws + 14942208u);
  unsigned short* bout_c  = (unsigned short*)(ws + 14945280u);

  // K/V scratch in d_out's bank region; combine_bank rewrites it afterwards.
  unsigned short* kv = (unsigned short*)(outf + 1048576);
  unsigned short* k_s  = kv;             // 8 MB: [h][m][d] swizzled
  unsigned short* vT_s = kv + 4194304;   // 8 MB: [h][d][m] keyperm+swizzled

  convert_all<<<6146, 256, 0, stream>>>(query, bank, Win, bin, Wout, bout,
                                        q_c, bank_c, Win_c, bin_c, Wout_c, bout_c);

  proj_fused<<<640, 256, 0, stream>>>(q_c, bank_c, Win_c, bin_c, q_s, k_s, vT_s);

  attn_partial<<<512, 256, 0, stream>>>(q_s, k_s, vT_s, O_part, l_part);

  combine_bank<<<5120, 256, 0, stream>>>(O_part, l_part, a_stage,
                                         memry, bank, ptrp, outf + 1048576);

  out_proj<<<dim3(8, 16), 256, 0, stream>>>(a_stage, Wout_c, bout_c, outf);
}

// Round 5
// 167.727 us; speedup vs baseline: 1.6821x; 1.1783x over previous
//
#include <hip/hip_runtime.h>

// ---------------------------------------------------------------------------
// LongTermMemoryModule, round 13. FP32 in/out. Changes vs r12 (FAILED):
//  - ONE BUG FIX in proj_fused::stage(): the global source address must be
//    LINEAR (copy the pre-swizzled global verbatim into LDS; rule #21).
//    r12 applied the XOR in the source too, un-swizzling the data during
//    staging, so the read-side XOR fetched wrong k-chunks (absmax 0.33,
//    and the 163K bank conflicts were the mismatched-pattern signature).
//    A and B operands use per-row XOR keys (i&7 vs j&7), so mismatched
//    k-slices were multiplied.
//  - Everything else identical to r12: 2-phase gload_lds proj GEMM,
//    pre-swizzled q_c/bank_c/Win_c, r11 attn, fused epilogue copy-outs.
// Shapes: B=32 S=64 D=512 M=8192 H=8 hd=64.
// ---------------------------------------------------------------------------

#define Dm  512
#define Mb  8192
#define BSr 2048

// 0.125 (1/sqrt(hd)) * log2(e): exp2 after pre-scaled QK == softmax exp
#define QSCALE 0.18033688011112042f

typedef float f32x4 __attribute__((ext_vector_type(4)));
typedef short bf16x4 __attribute__((ext_vector_type(4)));
typedef short bf16x8 __attribute__((ext_vector_type(8)));
typedef unsigned short u16x4 __attribute__((ext_vector_type(4)));
typedef unsigned short u16x8 __attribute__((ext_vector_type(8)));
typedef unsigned u32x4 __attribute__((ext_vector_type(4)));

#define MFMA(a, b, c) __builtin_amdgcn_mfma_f32_16x16x32_bf16((a), (b), (c), 0, 0, 0)

#if __has_builtin(__builtin_amdgcn_exp2f)
#define EXP2F(x) __builtin_amdgcn_exp2f(x)
#else
#define EXP2F(x) __expf((x)*0.6931471805599453f)
#endif

__device__ __forceinline__ unsigned short f32_bf16(float f) {
  unsigned u = __builtin_bit_cast(unsigned, f);
  u += 0x7FFFu + ((u >> 16) & 1u);   // RNE
  return (unsigned short)(u >> 16);
}
__device__ __forceinline__ float bf16_f32(unsigned short h) {
  unsigned u = ((unsigned)h) << 16;
  return __builtin_bit_cast(float, u);
}
__device__ __forceinline__ unsigned pack_bf16_trunc(float a, float b) {
  return (__builtin_bit_cast(unsigned, a) >> 16) |
         (__builtin_bit_cast(unsigned, b) & 0xFFFF0000u);
}

// async global(16B/lane) -> LDS(wave-uniform base + lane*16)
__device__ __forceinline__ void gload16(const unsigned short* g, unsigned short* l) {
  __builtin_amdgcn_global_load_lds(
      (const __attribute__((address_space(1))) void*)g,
      (__attribute__((address_space(3))) void*)l, 16, 0, 0);
}

// ---------------------------------------------------------------------------
// Merged fp32 -> bf16 canonicalization. q_c / bank_c / Win_c are written in
// the bank-swizzled layout (16B chunk c8 stored at c8 ^ (row&7)): proj's
// global_load_lds staging copies them verbatim (linear) into LDS and its
// ds_reads apply the same XOR.
// ---------------------------------------------------------------------------
__global__ __launch_bounds__(256) void convert_all(
    const float* __restrict__ q, const float* __restrict__ bank,
    const float* __restrict__ Win, const float* __restrict__ bin,
    const float* __restrict__ Wout, const float* __restrict__ bout,
    unsigned short* __restrict__ q_c, unsigned short* __restrict__ bank_c,
    unsigned short* __restrict__ Win_c, unsigned short* __restrict__ bin_c,
    unsigned short* __restrict__ Wout_c, unsigned short* __restrict__ bout_c) {
  const int e = (blockIdx.x * 256 + threadIdx.x) * 4;
  const float* src; unsigned short* dst; int off; int sw;
  if (e < 1048576)      { src = q;    dst = q_c;    off = e;           sw = 1; }
  else if (e < 5242880) { src = bank; dst = bank_c; off = e - 1048576; sw = 1; }
  else if (e < 6029312) { src = Win;  dst = Win_c;  off = e - 5242880; sw = 1; }
  else if (e < 6030848) { src = bin;  dst = bin_c;  off = e - 6029312; sw = 0; }
  else if (e < 6292992) { src = Wout; dst = Wout_c; off = e - 6030848; sw = 0; }
  else                  { src = bout; dst = bout_c; off = e - 6292992; sw = 0; }
  f32x4 v = *(const f32x4*)(src + off);
  u16x4 o;
#pragma unroll
  for (int j = 0; j < 4; ++j) o[j] = f32_bf16(v[j]);
  int doff = off;
  if (sw) {
    const int row = off >> 9, col = off & 511;
    doff = (off & ~511) | ((((col >> 3) ^ (row & 7)) << 3) | (col & 7));
  }
  *(u16x4*)(dst + doff) = o;
}

// ---------------------------------------------------------------------------
// Fused projections, 2-phase LDS-staged GEMM.
// Blocks [0,512): K+V proj. idx&7 <-> XCD groups blocks sharing bank rows;
//   h=(idx>>3)&7; M-tile 128, N = Wk64|Wv64, BK=64, 8 strips.
// Blocks [512,576): Q proj. 128x128 tiles of the 2048x512 GEMM.
// Waves: 2M x 2N split, acc[4][4] each. Epilogues: K/V -> Kst/Vst LDS
// re-stage -> key-perm + bank-swizzled coalesced copy-out (r11 verified);
// Q -> blocked q_s scalar stores with bias + QSCALE.
// ---------------------------------------------------------------------------
__global__ __launch_bounds__(256, 2) void proj_fused(
    const unsigned short* __restrict__ q_c,     // swizzled
    const unsigned short* __restrict__ bank_c,  // swizzled
    const unsigned short* __restrict__ Win_c,   // swizzled
    const unsigned short* __restrict__ bin_c,
    unsigned short* __restrict__ q_s,
    unsigned short* __restrict__ k_s,
    unsigned short* __restrict__ vT_s) {
  __shared__ __align__(16) unsigned short sh[32768];  // 64 KB
  const int lane = threadIdx.x & 63;
  const int wv   = threadIdx.x >> 6;
  const int l15  = lane & 15;
  const int qd   = lane >> 4;
  const int mh   = wv & 1;    // wave m-half
  const int nh   = wv >> 1;   // wave n-half (K/V: 0=K cols, 1=V cols)

  const unsigned short *Ag, *B0, *B1;
  int h = 0, mbase, nbase = 0;
  const bool iskv = blockIdx.x < 512;
  if (iskv) {
    const int idx = blockIdx.x;
    h     = (idx >> 3) & 7;
    mbase = ((idx & 7) * 8 + (idx >> 6)) * 128;
    Ag = bank_c + mbase * Dm;
    B0 = Win_c + (Dm + h * 64) * Dm;        // Wk rows (row&7 preserved)
    B1 = Win_c + (2 * Dm + h * 64) * Dm;    // Wv rows
  } else {
    const int idx = blockIdx.x - 512;
    mbase = (idx >> 2) * 128;
    nbase = (idx & 3) * 128;
    Ag = q_c + mbase * Dm;
    B0 = Win_c + nbase * Dm;
    B1 = Win_c + (nbase + 64) * Dm;
  }

  // LDS: A dbuf [2][128*64] at 0, B dbuf [2][128*64] at 16384 (elems)
  auto Ab = [&](int buf) { return sh + buf * 8192; };
  auto Bb = [&](int buf) { return sh + 16384 + buf * 8192; };

  // stage strip t into buffer buf: 4+4 x gload16 per thread.
  // Source address LINEAR: global already holds the swizzled layout; the
  // DMA copies it verbatim, ds_reads below apply the XOR. (r12's bug was
  // XORing here too, which un-swizzled the LDS contents.)
  auto stage = [&](int buf, int t) {
#pragma unroll
    for (int i = 0; i < 4; ++i) {
      const int chunk = i * 256 + wv * 64 + lane;
      const int row = chunk >> 3, c8 = chunk & 7;
      gload16(Ag + row * Dm + (t * 8 + c8) * 8,
              Ab(buf) + (i * 256 + wv * 64) * 8);
    }
#pragma unroll
    for (int i = 0; i < 4; ++i) {
      const int chunk = i * 256 + wv * 64 + lane;
      const int row = chunk >> 3, c8 = chunk & 7;
      const unsigned short* wb = (row < 64) ? B0 + row * Dm : B1 + (row - 64) * Dm;
      gload16(wb + (t * 8 + c8) * 8,
              Bb(buf) + (i * 256 + wv * 64) * 8);
    }
  };

  const f32x4 z4 = {0.f, 0.f, 0.f, 0.f};
  f32x4 acc[4][4];
#pragma unroll
  for (int mt = 0; mt < 4; ++mt)
#pragma unroll
    for (int nt = 0; nt < 4; ++nt) acc[mt][nt] = z4;

  auto compute = [&](int buf) {
#pragma unroll
    for (int ks = 0; ks < 2; ++ks) {
      bf16x8 af[4], bfr[4];
#pragma unroll
      for (int mt = 0; mt < 4; ++mt) {
        const int row = mh * 64 + mt * 16 + l15;
        af[mt] = *(const bf16x8*)(Ab(buf) + row * 64 + (((ks * 4 + qd) ^ (row & 7)) * 8));
      }
#pragma unroll
      for (int nt = 0; nt < 4; ++nt) {
        const int row = nh * 64 + nt * 16 + l15;
        bfr[nt] = *(const bf16x8*)(Bb(buf) + row * 64 + (((ks * 4 + qd) ^ (row & 7)) * 8));
      }
#pragma unroll
      for (int mt = 0; mt < 4; ++mt)
#pragma unroll
        for (int nt = 0; nt < 4; ++nt)
          acc[mt][nt] = MFMA(af[mt], bfr[nt], acc[mt][nt]);
    }
  };

  // --- 2-phase main loop: 8 strips of BK=64 ---
  stage(0, 0);
  __asm__ volatile("s_waitcnt vmcnt(0)" ::: "memory");
  __syncthreads();
#pragma unroll 1
  for (int t = 0; t < 7; ++t) {
    stage((t + 1) & 1, t + 1);
    compute(t & 1);
    __asm__ volatile("s_waitcnt vmcnt(0)" ::: "memory");
    __syncthreads();
  }
  compute(1);
  __syncthreads();  // epilogue aliases the staging LDS

  if (iskv) {
    unsigned short* Kst = sh;          // [128][72]
    unsigned short* Vst = sh + 16384;  // [64][136]
    if (nh == 0) {
#pragma unroll
      for (int nt = 0; nt < 4; ++nt) {
        const int d = nt * 16 + l15;
        const float bk = bf16_f32(bin_c[Dm + h * 64 + d]);
#pragma unroll
        for (int mt = 0; mt < 4; ++mt)
#pragma unroll
          for (int r = 0; r < 4; ++r) {
            const int m = mh * 64 + mt * 16 + qd * 4 + r;
            Kst[m * 72 + d] = f32_bf16(acc[mt][nt][r] + bk);
          }
      }
    } else {
#pragma unroll
      for (int nt = 0; nt < 4; ++nt) {
        const int d = nt * 16 + l15;
        const float bv = bf16_f32(bin_c[2 * Dm + h * 64 + d]);
#pragma unroll
        for (int mt = 0; mt < 4; ++mt)
#pragma unroll
          for (int r = 0; r < 4; ++r) {
            const int m = mh * 64 + mt * 16 + qd * 4 + r;
            Vst[d * 136 + m] = f32_bf16(acc[mt][nt][r] + bv);
          }
      }
    }
    __syncthreads();
    // K copy-out: bank-swizzled 16B chunks, coalesced
#pragma unroll
    for (int p = 0; p < 4; ++p) {
      const int m  = p * 32 + (threadIdx.x >> 3);
      const int c8 = threadIdx.x & 7;
      *(u16x8*)(k_s + h * (Mb * 64) + (mbase + m) * 64 + ((c8 ^ (m & 7)) * 8)) =
          *(const u16x8*)(Kst + m * 72 + c8 * 8);
    }
    // V copy-out: key permutation in source gather + bank swizzle in dest
#pragma unroll
    for (int p = 0; p < 4; ++p) {
      const int d    = p * 16 + (threadIdx.x >> 4);
      const int m16  = threadIdx.x & 15;
      const int base = (m16 >> 2) * 32;
      const int q4   = (m16 & 3) * 4;
      u16x4 lo = *(const u16x4*)(Vst + d * 136 + base + q4);
      u16x4 hi = *(const u16x4*)(Vst + d * 136 + base + 16 + q4);
      u16x8 o  = __builtin_shufflevector(lo, hi, 0, 1, 2, 3, 4, 5, 6, 7);
      *(u16x8*)(vT_s + (h * 64 + d) * Mb + mbase + ((m16 ^ (d & 7)) * 8)) = o;
    }
  } else {
    // Q epilogue: blocked q_s layout, bias + QSCALE, bf16 scalar stores
#pragma unroll
    for (int nt = 0; nt < 4; ++nt) {
      const int n = nbase + nh * 64 + nt * 16 + l15;
      const float bf = bf16_f32(bin_c[n]);
#pragma unroll
      for (int mt = 0; mt < 4; ++mt)
#pragma unroll
        for (int r = 0; r < 4; ++r) {
          const int m = mbase + mh * 64 + mt * 16 + qd * 4 + r;
          const unsigned idx = ((unsigned)(m >> 6) * 8u + (unsigned)(n >> 6)) * 4096u +
                               (unsigned)(m & 63) * 64u + (unsigned)(n & 63);
          q_s[idx] = f32_bf16((acc[mt][nt][r] + bf) * QSCALE);
        }
    }
  }
}

// ---------------------------------------------------------------------------
// Attention partial, 2-phase LDS-staged (r11, unchanged).
// ---------------------------------------------------------------------------
__global__ __launch_bounds__(256, 2) void attn_partial(
    const unsigned short* __restrict__ q_s,   // [bh][s][d], pre-scaled
    const unsigned short* __restrict__ k_s,   // [h][m][d] swizzled
    const unsigned short* __restrict__ vT_s,  // [h][d][m] keyperm+swizzled
    unsigned short* __restrict__ O_part,      // [bh][part][s][d] bf16
    float* __restrict__ l_part) {             // [bh][part][s]
  __shared__ __align__(16) unsigned short Kbuf[2][128 * 64];  // 2 x 16 KB
  __shared__ __align__(16) unsigned short Vbuf[2][64 * 128];  // 2 x 16 KB

  const int lane = threadIdx.x & 63;
  const int wv   = threadIdx.x >> 6;
  const int l15  = lane & 15;
  const int qd   = lane >> 4;
  const int h    = blockIdx.x & 7;            // XCD = bid % 8 == h
  const int g    = blockIdx.x >> 3;
  const int part = g & 3;
  const int b    = (g >> 2) * 2 + (wv >> 1);
  const int bh   = b * 8 + h;
  const int s0   = (wv & 1) * 32;

  const unsigned short* kp = k_s  + h * (Mb * 64);
  const unsigned short* vp = vT_s + h * (Mb * 64);
  const int m0p = part * 2048;

  bf16x8 bQ[2][2];
  {
    const unsigned short* qp = q_s + bh * 4096;
#pragma unroll
    for (int sj = 0; sj < 2; ++sj)
#pragma unroll
      for (int ks = 0; ks < 2; ++ks)
        bQ[sj][ks] = *(const bf16x8*)(qp + (s0 + sj * 16 + l15) * 64 + ks * 32 + qd * 8);
  }

  const f32x4 z4 = {0.f, 0.f, 0.f, 0.f};
  f32x4 oacc[2][4];
  float lsum[2] = {0.f, 0.f};
#pragma unroll
  for (int sj = 0; sj < 2; ++sj)
#pragma unroll
    for (int dt = 0; dt < 4; ++dt) oacc[sj][dt] = z4;

  const int swz = (l15 & 7) * 8;

  auto stage = [&](int buf, int m0) {
    const unsigned short* gk = kp + (m0 + wv * 32 + (lane >> 3)) * 64 + (lane & 7) * 8;
    unsigned short* lk = &Kbuf[buf][(wv * 32) * 64];
#pragma unroll
    for (int i = 0; i < 4; ++i) gload16(gk + i * 8 * 64, lk + i * 8 * 64);
    const unsigned short* gv = vp + (wv * 16 + (lane >> 4)) * Mb + m0 + (lane & 15) * 8;
    unsigned short* lv = &Vbuf[buf][(wv * 16) * 128];
#pragma unroll
    for (int i = 0; i < 4; ++i) gload16(gv + i * 4 * Mb, lv + i * 4 * 128);
  };

  auto compute = [&](int buf) {
    const unsigned short* Kb = Kbuf[buf];
    const unsigned short* Vb = Vbuf[buf];
#pragma unroll
    for (int c2 = 0; c2 < 2; ++c2) {
      f32x4 sfr[4][2];
#pragma unroll
      for (int kt = 0; kt < 4; ++kt)
#pragma unroll
        for (int sj = 0; sj < 2; ++sj) sfr[kt][sj] = z4;
#pragma unroll
      for (int kt = 0; kt < 4; ++kt) {
        const int row = c2 * 64 + kt * 16 + l15;
#pragma unroll
        for (int ks = 0; ks < 2; ++ks) {
          bf16x8 aK = *(const bf16x8*)(Kb + row * 64 + ((ks * 32 + qd * 8) ^ swz));
#pragma unroll
          for (int sj = 0; sj < 2; ++sj)
            sfr[kt][sj] = MFMA(aK, bQ[sj][ks], sfr[kt][sj]);
        }
      }
      bf16x8 aP[2][2];
#pragma unroll
      for (int sj = 0; sj < 2; ++sj) {
#pragma unroll
        for (int c = 0; c < 2; ++c) {
          const f32x4 lo = sfr[c * 2][sj];
          const f32x4 hi = sfr[c * 2 + 1][sj];
          float e0 = EXP2F(lo[0]), e1 = EXP2F(lo[1]);
          float e2 = EXP2F(lo[2]), e3 = EXP2F(lo[3]);
          float e4 = EXP2F(hi[0]), e5 = EXP2F(hi[1]);
          float e6 = EXP2F(hi[2]), e7 = EXP2F(hi[3]);
          lsum[sj] += ((e0 + e1) + (e2 + e3)) + ((e4 + e5) + (e6 + e7));
          u32x4 pk;
          pk[0] = pack_bf16_trunc(e0, e1);
          pk[1] = pack_bf16_trunc(e2, e3);
          pk[2] = pack_bf16_trunc(e4, e5);
          pk[3] = pack_bf16_trunc(e6, e7);
          aP[sj][c] = __builtin_bit_cast(bf16x8, pk);
        }
      }
#pragma unroll
      for (int c = 0; c < 2; ++c) {
#pragma unroll
        for (int dt = 0; dt < 4; ++dt) {
          const int d = dt * 16 + l15;
          bf16x8 bV = *(const bf16x8*)(Vb + d * 128 + ((c2 * 64 + c * 32 + qd * 8) ^ swz));
#pragma unroll
          for (int sj = 0; sj < 2; ++sj)
            oacc[sj][dt] = MFMA(aP[sj][c], bV, oacc[sj][dt]);
        }
      }
    }
  };

  stage(0, m0p);
  __asm__ volatile("s_waitcnt vmcnt(0)" ::: "memory");
  __syncthreads();
#pragma unroll 1
  for (int t = 0; t < 15; ++t) {
    stage((t + 1) & 1, m0p + (t + 1) * 128);
    compute(t & 1);
    __asm__ volatile("s_waitcnt vmcnt(0)" ::: "memory");
    __syncthreads();
  }
  compute(1);

#pragma unroll
  for (int sj = 0; sj < 2; ++sj) {
    float v = lsum[sj];
    v += __shfl_xor(v, 16);
    v += __shfl_xor(v, 32);
    if (qd == 0) l_part[(bh * 4 + part) * 64 + s0 + sj * 16 + l15] = v;
  }

  unsigned short* Ob = O_part + (bh * 4 + part) * 4096;
#pragma unroll
  for (int sj = 0; sj < 2; ++sj)
#pragma unroll
    for (int dt = 0; dt < 4; ++dt)
#pragma unroll
      for (int r = 0; r < 4; ++r)
        Ob[(s0 + sj * 16 + qd * 4 + r) * 64 + dt * 16 + l15] = f32_bf16(oacc[sj][dt][r]);
}

// ---------------------------------------------------------------------------
// Fused combine + bank rewrite (unchanged).
// ---------------------------------------------------------------------------
__global__ __launch_bounds__(256) void combine_bank(
    const unsigned short* __restrict__ O_part, const float* __restrict__ l_part,
    unsigned short* __restrict__ a_stage,
    const float* __restrict__ memory, const float* __restrict__ bank,
    const int* __restrict__ ptrp, float* __restrict__ out_bank) {
  if (blockIdx.x < 1024) {
    const int e  = (blockIdx.x * 256 + threadIdx.x) * 4;  // < 1048576
    const int bh = e >> 12;
    const int rem = e & 4095;
    const int s  = rem >> 6;
    const int d  = rem & 63;
    float acc[4] = {0.f, 0.f, 0.f, 0.f};
    float l = 0.f;
#pragma unroll
    for (int p = 0; p < 4; ++p) {
      u16x4 v = *(const u16x4*)(O_part + (bh * 4 + p) * 4096 + rem);
#pragma unroll
      for (int j = 0; j < 4; ++j) acc[j] += bf16_f32(v[j]);
      l += l_part[(bh * 4 + p) * 64 + s];
    }
    const int b = bh >> 3, h = bh & 7;
    u16x4 o;
#pragma unroll
    for (int j = 0; j < 4; ++j) o[j] = f32_bf16(acc[j] / l);
    *(u16x4*)(a_stage + (b * 64 + s) * 512 + h * 64 + d) = o;
  } else {
    const int t  = (blockIdx.x - 1024) * 256 + threadIdx.x;  // < 1,048,576
    const int r  = t >> 7;
    const int c4 = (t & 127) * 4;
    const int ptr = ptrp[0];
    const unsigned off = (unsigned)(r - ptr + Mb) & (Mb - 1);
    const float* src = (off < (unsigned)BSr) ? memory + off * Dm + c4
                                             : bank + r * Dm + c4;
    *(f32x4*)(out_bank + r * Dm + c4) = *(const f32x4*)src;
  }
}

// ---------------------------------------------------------------------------
// retrieved[m,n] = a_stage[m,:] @ Wout[n,:] + bout[n]  -> fp32 d_out
// (unchanged).
// ---------------------------------------------------------------------------
__global__ __launch_bounds__(256) void out_proj(
    const unsigned short* __restrict__ A,
    const unsigned short* __restrict__ W,
    const unsigned short* __restrict__ bias,
    float* __restrict__ out) {
  const int lane = threadIdx.x & 63;
  const int wv   = threadIdx.x >> 6;
  const int l15  = lane & 15;
  const int qd   = lane >> 4;
  const int mbase = blockIdx.y * 128 + wv * 32;
  const int nbase = blockIdx.x * 64;

  const f32x4 z4 = {0.f, 0.f, 0.f, 0.f};
  f32x4 acc[2][4];
#pragma unroll
  for (int ti = 0; ti < 2; ++ti)
#pragma unroll
    for (int j = 0; j < 4; ++j) acc[ti][j] = z4;

  const unsigned short* a0p = A + (mbase + l15) * Dm + qd * 8;
  const unsigned short* a1p = a0p + 16 * Dm;
  const unsigned short* wp  = W + (nbase + l15) * Dm + qd * 8;

#pragma unroll 4
  for (int k0 = 0; k0 < Dm; k0 += 32) {
    bf16x8 a0 = *(const bf16x8*)(a0p + k0);
    bf16x8 a1 = *(const bf16x8*)(a1p + k0);
#pragma unroll
    for (int j = 0; j < 4; ++j) {
      bf16x8 bfr = *(const bf16x8*)(wp + j * 16 * Dm + k0);
      acc[0][j] = MFMA(a0, bfr, acc[0][j]);
      acc[1][j] = MFMA(a1, bfr, acc[1][j]);
    }
  }

#pragma unroll
  for (int ti = 0; ti < 2; ++ti) {
#pragma unroll
    for (int j = 0; j < 4; ++j) {
      const int n = nbase + j * 16 + l15;
      const float bf = bf16_f32(bias[n]);
#pragma unroll
      for (int r = 0; r < 4; ++r) {
        const int m = mbase + ti * 16 + qd * 4 + r;
        out[m * Dm + n] = acc[ti][j][r] + bf;
      }
    }
  }
}

// ---------------------------------------------------------------------------
extern "C" void kernel_launch(void* const* d_in, const int* in_sizes, int n_in,
                              void* d_out, int out_size, void* d_ws, size_t ws_size,
                              hipStream_t stream) {
  const float* query = (const float*)d_in[0];
  const float* memry = (const float*)d_in[1];
  const float* bank  = (const float*)d_in[2];
  const float* Win   = (const float*)d_in[3];
  const float* bin   = (const float*)d_in[4];
  const float* Wout  = (const float*)d_in[5];
  const float* bout  = (const float*)d_in[6];
  const int*   ptrp  = (const int*)d_in[7];
  float* outf = (float*)d_out;

  // ws layout (14.3 MB; 15.8 MB proven). Lifetime-disjoint aliases:
  // a_stage reuses q_c; O_part reuses bank_c.
  char* ws = (char*)d_ws;
  unsigned short* q_c     = (unsigned short*)(ws);                 //  0 ..  2 MB
  unsigned short* a_stage = (unsigned short*)(ws);                 //  (alias)
  unsigned short* bank_c  = (unsigned short*)(ws + (2u << 20));    //  2 .. 10 MB
  unsigned short* O_part  = (unsigned short*)(ws + (2u << 20));    //  (alias)
  unsigned short* Win_c   = (unsigned short*)(ws + (10u << 20));   // 10 .. 11.5 MB
  unsigned short* Wout_c  = (unsigned short*)(ws + 12058624u);     // 11.5 .. 12 MB
  unsigned short* q_s     = (unsigned short*)(ws + (12u << 20));   // 12 .. 14 MB
  float*          l_part  = (float*)(ws + (14u << 20));            // 14 .. 14.25 MB
  unsigned short* bin_c   = (unsigned short*)(ws + 14942208u);
  unsigned short* bout_c  = (unsigned short*)(ws + 14945280u);

  // K/V scratch in d_out's bank region; combine_bank rewrites it afterwards.
  unsigned short* kv = (unsigned short*)(outf + 1048576);
  unsigned short* k_s  = kv;             // 8 MB: [h][m][d] swizzled
  unsigned short* vT_s = kv + 4194304;   // 8 MB: [h][d][m] keyperm+swizzled

  convert_all<<<6146, 256, 0, stream>>>(query, bank, Win, bin, Wout, bout,
                                        q_c, bank_c, Win_c, bin_c, Wout_c, bout_c);

  proj_fused<<<576, 256, 0, stream>>>(q_c, bank_c, Win_c, bin_c, q_s, k_s, vT_s);

  attn_partial<<<512, 256, 0, stream>>>(q_s, k_s, vT_s, O_part, l_part);

  combine_bank<<<5120, 256, 0, stream>>>(O_part, l_part, a_stage,
                                         memry, bank, ptrp, outf + 1048576);

  out_proj<<<dim3(8, 16), 256, 0, stream>>>(a_stage, Wout_c, bout_c, outf);
}